// Round 2
// baseline (356.693 us; speedup 1.0000x reference)
//
#include <hip/hip_runtime.h>
#include <hip/hip_fp16.h>
#include <math.h>

// ---------------------------------------------------------------------------
// GAT model forward. N=100k nodes, E=1.6M edges, HID=64.
// R18 = R17 with the packed-fp16 math rewritten on clang native _Float16
// ext-vectors (v_pk_add/v_pk_fma/v_pk_max via __builtin_elementwise_max)
// instead of the __half2 API (ROCm 7.2 lacks a usable __hmax2 overload).
// Theory vs R16 (354.6us) unchanged:
//  - k_edge_head: packed fp16 MLP cuts per-edge VALU ~2.3x; 4-edge unroll
//    (2x gathers in flight); nontemporal hints on read-once streams.
//    Kernel was latency-bound (VALU 46%, HBM 39%, MFMA 0) -- issue-rate fix,
//    byte count (184MB 8-XCD replication floor) unchanged by design.
//  - everything else byte-identical to R16.
// ---------------------------------------------------------------------------

typedef _Float16 half8_t __attribute__((ext_vector_type(8)));
typedef _Float16 half2_t __attribute__((ext_vector_type(2)));
typedef float floatx4 __attribute__((ext_vector_type(4)));

#if defined(__has_builtin)
#if __has_builtin(__builtin_amdgcn_fdot2)
#define HAS_FDOT2 1
#endif
#if __has_builtin(__builtin_elementwise_max)
#define HAS_EMAX 1
#endif
#endif

static __device__ __forceinline__ float fdot2_acc(half2_t a, half2_t b, float c){
#ifdef HAS_FDOT2
  return __builtin_amdgcn_fdot2(a, b, c, false);
#else
  return fmaf((float)a[0], (float)b[0], fmaf((float)a[1], (float)b[1], c));
#endif
}

static __device__ __forceinline__ half2_t leaky2(half2_t t, half2_t slope){
#ifdef HAS_EMAX
  return __builtin_elementwise_max(t, t * slope);     // v_pk_max_f16
#else
  half2_t r;
  r[0] = t[0] > (_Float16)0 ? t[0] : t[0] * slope[0];
  r[1] = t[1] > (_Float16)0 ? t[1] : t[1] * slope[1];
  return r;
#endif
}

static __device__ __forceinline__ float2 ldnt_f2(const float2* p){
  union { unsigned long long u; float2 f; } x;
  x.u = __builtin_nontemporal_load((const unsigned long long*)p);
  return x.f;
}

// Phase 1: bucket edges by dst>>7 (rank trick). Block 0 also computes
// vsd = [g2W@g2as ; g2W@g2ad] for k_hw_mfma's factored alpha MFMA.
// Then grid-stride fuse1 tail: hw1 = fp16(x@Mc+c), H=4 alphas.
// blockDim = 512 (8 waves) for latency-bound occupancy.
__global__ __launch_bounds__(512) void k_scatter_fuse(
    const int* __restrict__ src, const int* __restrict__ dst,
    int E, int NB, int cap, int* cursor,
    unsigned int* __restrict__ ebuf,
    const float* __restrict__ x,
    const float* __restrict__ encW, const float* __restrict__ encb,
    const float* __restrict__ g1W,
    const float* __restrict__ g1as, const float* __restrict__ g1ad,
    const float* __restrict__ g2W,
    const float* __restrict__ g2as, const float* __restrict__ g2ad,
    float* __restrict__ vsd,
    __half* __restrict__ hw, float* __restrict__ alpha_s,
    float* __restrict__ alpha_d, int n){
  __shared__ int hist[800];
  __shared__ int base[800];
  __shared__ float McS[192];
  int t = threadIdx.x;                  // blockDim = 512
  if (t < 64){                          // per-block Mc (g1W is L2-resident)
    float m0 = 0.f, m1 = 0.f, cc = 0.f;
    for (int k = 0; k < 64; ++k){
      float g = g1W[k * 64 + t];
      m0 = fmaf(encW[k], g, m0);
      m1 = fmaf(encW[64 + k], g, m1);
      cc = fmaf(encb[k], g, cc);
    }
    McS[t] = m0; McS[64 + t] = m1; McS[128 + t] = cc;
  }
  if (blockIdx.x == 0 && t >= 64 && t < 128){  // vsd on a different wave
    int k = t - 64;
    float vs = 0.f, vd = 0.f;
    for (int ch = 0; ch < 64; ++ch){
      float g = g2W[k * 64 + ch];
      vs = fmaf(g, g2as[ch], vs);
      vd = fmaf(g, g2ad[ch], vd);
    }
    vsd[k] = vs; vsd[64 + k] = vd;
  }
  for (int i = t; i < NB; i += 512) hist[i] = 0;
  __syncthreads();
  int cbase = blockIdx.x * 2048;
  int sv[4], bk[4], dl[4], rk[4];
  #pragma unroll
  for (int i = 0; i < 4; ++i){
    int e = cbase + i * 512 + t;
    if (e < E){
      int d = dst[e];
      sv[i] = src[e]; bk[i] = d >> 7; dl[i] = d & 127;
      rk[i] = atomicAdd(&hist[bk[i]], 1);   // rank within (block,bucket)
    } else bk[i] = -1;
  }
  __syncthreads();
  for (int i = t; i < NB; i += 512){
    int c = hist[i];
    base[i] = (c > 0) ? (i * cap + atomicAdd(&cursor[i], c)) : 0;
  }
  __syncthreads();
  #pragma unroll
  for (int i = 0; i < 4; ++i){
    if (bk[i] >= 0){
      int p = base[bk[i]] + rk[i];
      if (p < (bk[i] + 1) * cap)        // overflow guard (never fires in practice)
        ebuf[p] = (unsigned)sv[i] | ((unsigned)dl[i] << 17);
    }
  }
  // ---- fuse1 tail: grid-stride over n*64 channels ----
  int total = n * 64;
  int lane = t & 63;
  for (int idx = blockIdx.x * 512 + t; idx < total; idx += gridDim.x * 512){
    int node = idx >> 6;                // j == lane (idx base multiple of 64)
    float acc = fmaf(x[node * 2 + 0], McS[lane],
                fmaf(x[node * 2 + 1], McS[64 + lane], McS[128 + lane]));
    hw[idx] = __float2half(acc);
    float ps = acc * g1as[lane];
    float pd = acc * g1ad[lane];
    #pragma unroll
    for (int off = 1; off < 16; off <<= 1){
      ps += __shfl_xor(ps, off);
      pd += __shfl_xor(pd, off);
    }
    if ((lane & 15) == 0){
      int h = lane >> 4;
      alpha_s[node * 4 + h] = ps;
      alpha_d[node * 4 + h] = pd;
    }
  }
}

// Phase 2: one block (256 thr) per 128-node bucket. Sort in LDS ->
// rowrange (int2) + dst-sorted packed ebuf.
__global__ void k_bucket_build(const int* __restrict__ cursor, int cap, int N,
                               unsigned int* ebuf, int2* __restrict__ rowrange){
  __shared__ unsigned int ent[2700];
  __shared__ unsigned short rank[2700];
  __shared__ int cnts[128];
  __shared__ int aux[128];
  int b = blockIdx.x, t = threadIdx.x;  // blockDim = 256
  int base = b * cap;
  int cnt = cursor[b];
  if (cnt > cap) cnt = cap;
  for (int i = t; i < cnt; i += 256) ent[i] = ebuf[base + i];
  if (t < 128) cnts[t] = 0;
  __syncthreads();
  for (int i = t; i < cnt; i += 256)
    rank[i] = (unsigned short)atomicAdd(&cnts[ent[i] >> 17], 1);
  __syncthreads();
  int v = 0;
  if (t < 128){ v = cnts[t]; aux[t] = v; }
  __syncthreads();
  for (int off = 1; off < 128; off <<= 1){
    int x = 0;
    if (t < 128 && t >= off) x = aux[t - off];
    __syncthreads();
    if (t < 128) aux[t] += x;
    __syncthreads();
  }
  if (t < 128){
    int incl = aux[t];
    int node = (b << 7) + t;
    if (node < N) rowrange[node] = make_int2(base + incl - v, base + incl);
    cnts[t] = incl - v;                 // per-node segment start (no atomics)
  }
  __syncthreads();
  for (int i = t; i < cnt; i += 256){
    unsigned int en = ent[i];
    int pos = cnts[en >> 17] + (int)rank[i];
    ebuf[base + pos] = en;              // keep packed (src|dl<<17)
  }
}

// MFMA GEMM: hw2 = fp16(h1 @ g2W); alphas via factored MFMA on wave 0:
// alpha_{s,d}[node] = h1[node,:] . vsd  (B cols [v_s|v_d|0..]).
// Zero barriers, zero LDS.
__global__ __launch_bounds__(256) void k_hw_mfma(
    const __half* __restrict__ hin, const float* __restrict__ W,
    const float* __restrict__ vsd,
    __half* __restrict__ hw, float* __restrict__ alpha_s,
    float* __restrict__ alpha_d, int n){
  int t = threadIdx.x;
  int lane = t & 63, wave = t >> 6;
  int l15 = lane & 15, quad = lane >> 4;
  int ch = wave * 16 + l15;
  half8_t b0, b1;
  #pragma unroll
  for (int j = 0; j < 8; ++j){
    b0[j] = (_Float16)W[(quad * 8 + j) * 64 + ch];
    b1[j] = (_Float16)W[(quad * 8 + j + 32) * 64 + ch];
  }
  half8_t bA0 = {0,0,0,0,0,0,0,0}, bA1 = {0,0,0,0,0,0,0,0};
  if (wave == 0 && l15 < 2){
    const float* v = vsd + l15 * 64;
    #pragma unroll
    for (int j = 0; j < 8; ++j){
      bA0[j] = (_Float16)v[quad * 8 + j];
      bA1[j] = (_Float16)v[quad * 8 + j + 32];
    }
  }
  int base = blockIdx.x * 64;
  for (int it = 0; it < 4; ++it){
    int tb = base + it * 16;
    if (tb >= n) break;
    int arn = tb + l15; if (arn >= n) arn = n - 1;
    const __half* arow = hin + (size_t)arn * 64 + quad * 8;
    half8_t a0 = *(const half8_t*)arow;
    half8_t a1 = *(const half8_t*)(arow + 32);
    floatx4 acc = {0.f, 0.f, 0.f, 0.f};
    acc = __builtin_amdgcn_mfma_f32_16x16x32_f16(a0, b0, acc, 0, 0, 0);
    acc = __builtin_amdgcn_mfma_f32_16x16x32_f16(a1, b1, acc, 0, 0, 0);
    #pragma unroll
    for (int r = 0; r < 4; ++r){
      int node = tb + quad * 4 + r;
      if (node < n) hw[(size_t)node * 64 + ch] = __float2half(acc[r]);
    }
    if (wave == 0){
      floatx4 accA = {0.f, 0.f, 0.f, 0.f};
      accA = __builtin_amdgcn_mfma_f32_16x16x32_f16(a0, bA0, accA, 0, 0, 0);
      accA = __builtin_amdgcn_mfma_f32_16x16x32_f16(a1, bA1, accA, 0, 0, 0);
      if (l15 < 2){
        float* dstp = (l15 == 0) ? alpha_s : alpha_d;
        #pragma unroll
        for (int r = 0; r < 4; ++r){
          int node = tb + quad * 4 + r;
          if (node < n) dstp[node] = accA[r];
        }
      }
    }
  }
}

// Wave = 1 destination node, 8 edge-groups x 8 lanes; lane jj owns channels
// 8jj..8jj+7 (one 16B fp16 load per edge). Numerator computed in-loop from
// the L2-resident alpha tables. [R8 gather structure: best measured.]
template<int H, bool ELU_ACT>
__global__ void k_agg(const __half* __restrict__ hw,
                      const float* __restrict__ alpha_s, const float* __restrict__ alpha_d,
                      const int2* __restrict__ rowrange,
                      const unsigned int* __restrict__ ebuf,
                      const float* __restrict__ bias, __half* __restrict__ hout, int n){
  int node = (blockIdx.x * blockDim.x + threadIdx.x) >> 6;
  int lane = threadIdx.x & 63;
  int g = lane >> 3, jj = lane & 7;
  if (node >= n) return;
  int hidx = (jj * H) >> 3;                // head of channels 8jj..8jj+7
  int2 rr = rowrange[node];
  int start = rr.x, end = rr.y;
  float adn = alpha_d[node * H + hidx];
  float acc[8] = {0.f,0.f,0.f,0.f,0.f,0.f,0.f,0.f};
  float psum = 0.f;
  if (g == 0){                             // self loop (group 0 only)
    float a = alpha_s[node * H + hidx] + adn;
    a = a > 0.f ? a : 0.2f * a;
    float p = __expf(a);
    psum = p;
    float4 rv = *(const float4*)(hw + (size_t)node * 64 + jj * 8);
    const __half2* hp = (const __half2*)&rv;
    #pragma unroll
    for (int k = 0; k < 4; ++k){
      float2 f = __half22float2(hp[k]);
      acc[2 * k] = p * f.x; acc[2 * k + 1] = p * f.y;
    }
  }
  int i = start + g;
  for (; i + 8 < end; i += 16){
    unsigned int e0 = ebuf[i], e1 = ebuf[i + 8];
    int s0 = e0 & 0x1FFFF, s1 = e1 & 0x1FFFF;
    float a0 = alpha_s[s0 * H + hidx] + adn;
    float a1 = alpha_s[s1 * H + hidx] + adn;
    a0 = a0 > 0.f ? a0 : 0.2f * a0;
    a1 = a1 > 0.f ? a1 : 0.2f * a1;
    float p0 = __expf(a0), p1 = __expf(a1);
    float4 r0 = *(const float4*)(hw + (size_t)s0 * 64 + jj * 8);
    float4 r1 = *(const float4*)(hw + (size_t)s1 * 64 + jj * 8);
    const __half2* h0 = (const __half2*)&r0;
    const __half2* h1 = (const __half2*)&r1;
    psum += p0 + p1;
    #pragma unroll
    for (int k = 0; k < 4; ++k){
      float2 f0 = __half22float2(h0[k]);
      float2 f1 = __half22float2(h1[k]);
      acc[2 * k]     = fmaf(p0, f0.x, fmaf(p1, f1.x, acc[2 * k]));
      acc[2 * k + 1] = fmaf(p0, f0.y, fmaf(p1, f1.y, acc[2 * k + 1]));
    }
  }
  if (i < end){
    unsigned int en = ebuf[i];
    int s = en & 0x1FFFF;
    float a = alpha_s[s * H + hidx] + adn;
    a = a > 0.f ? a : 0.2f * a;
    float p = __expf(a);
    float4 rv = *(const float4*)(hw + (size_t)s * 64 + jj * 8);
    const __half2* hp = (const __half2*)&rv;
    psum += p;
    #pragma unroll
    for (int k = 0; k < 4; ++k){
      float2 f = __half22float2(hp[k]);
      acc[2 * k]     = fmaf(p, f.x, acc[2 * k]);
      acc[2 * k + 1] = fmaf(p, f.y, acc[2 * k + 1]);
    }
  }
  #pragma unroll
  for (int off = 8; off < 64; off <<= 1){
    psum += __shfl_xor(psum, off);
    #pragma unroll
    for (int k = 0; k < 8; ++k) acc[k] += __shfl_xor(acc[k], off);
  }
  if (g == 0){
    float inv = 1.f / (psum + 1e-16f);
    float4 bv0 = ((const float4*)bias)[2 * jj];
    float4 bv1 = ((const float4*)bias)[2 * jj + 1];
    float o[8];
    o[0] = fmaf(acc[0], inv, bv0.x); o[1] = fmaf(acc[1], inv, bv0.y);
    o[2] = fmaf(acc[2], inv, bv0.z); o[3] = fmaf(acc[3], inv, bv0.w);
    o[4] = fmaf(acc[4], inv, bv1.x); o[5] = fmaf(acc[5], inv, bv1.y);
    o[6] = fmaf(acc[6], inv, bv1.z); o[7] = fmaf(acc[7], inv, bv1.w);
    if (ELU_ACT){
      #pragma unroll
      for (int k = 0; k < 8; ++k) o[k] = o[k] > 0.f ? o[k] : (__expf(o[k]) - 1.f);
    }
    half8_t hv;
    #pragma unroll
    for (int k = 0; k < 8; ++k) hv[k] = (_Float16)o[k];
    *(half8_t*)(hout + (size_t)node * 64 + jj * 8) = hv;
  }
}

// Fused heads GEMMs over h2 (fp16): P1/P2 fp16 + node head, 6 MFMAs/wave-tile.
__global__ __launch_bounds__(256) void k_heads_mfma(
    const __half* __restrict__ h, const float* __restrict__ eoW1,
    const float* __restrict__ noW1, const float* __restrict__ nob1,
    const float* __restrict__ noW2, const float* __restrict__ nob2,
    __half* __restrict__ P1, __half* __restrict__ P2,
    float* __restrict__ outN, int n){
  __shared__ float redP[4][16][2];
  int t = threadIdx.x;
  int lane = t & 63, wave = t >> 6;
  int l15 = lane & 15, quad = lane >> 4;
  int ch = wave * 16 + l15;
  half8_t bP1a, bP1b, bP2a, bP2b, bNa, bNb;
  #pragma unroll
  for (int j = 0; j < 8; ++j){
    int k0 = quad * 8 + j, k1 = k0 + 32;
    bP1a[j] = (_Float16)eoW1[k0 * 64 + ch];
    bP1b[j] = (_Float16)eoW1[k1 * 64 + ch];
    bP2a[j] = (_Float16)eoW1[(k0 + 64) * 64 + ch];
    bP2b[j] = (_Float16)eoW1[(k1 + 64) * 64 + ch];
    bNa[j]  = (_Float16)noW1[k0 * 64 + ch];
    bNb[j]  = (_Float16)noW1[k1 * 64 + ch];
  }
  float b1v = nob1[ch];
  float w20 = noW2[ch * 2 + 0], w21 = noW2[ch * 2 + 1];
  float b20 = nob2[0], b21 = nob2[1];
  int base = blockIdx.x * 64;
  for (int it = 0; it < 4; ++it){
    int tb = base + it * 16;
    if (tb >= n) break;
    int arn = tb + l15; if (arn >= n) arn = n - 1;
    const __half* arow = h + (size_t)arn * 64 + quad * 8;
    half8_t a0 = *(const half8_t*)arow;
    half8_t a1 = *(const half8_t*)(arow + 32);
    floatx4 ac1 = {0.f,0.f,0.f,0.f}, ac2 = {0.f,0.f,0.f,0.f}, acN = {0.f,0.f,0.f,0.f};
    ac1 = __builtin_amdgcn_mfma_f32_16x16x32_f16(a0, bP1a, ac1, 0, 0, 0);
    ac1 = __builtin_amdgcn_mfma_f32_16x16x32_f16(a1, bP1b, ac1, 0, 0, 0);
    ac2 = __builtin_amdgcn_mfma_f32_16x16x32_f16(a0, bP2a, ac2, 0, 0, 0);
    ac2 = __builtin_amdgcn_mfma_f32_16x16x32_f16(a1, bP2b, ac2, 0, 0, 0);
    acN = __builtin_amdgcn_mfma_f32_16x16x32_f16(a0, bNa, acN, 0, 0, 0);
    acN = __builtin_amdgcn_mfma_f32_16x16x32_f16(a1, bNb, acN, 0, 0, 0);
    float p0[4], p1[4];
    #pragma unroll
    for (int r = 0; r < 4; ++r){
      int node = tb + quad * 4 + r;
      if (node < n){
        P1[(size_t)node * 64 + ch] = __float2half(ac1[r]);
        P2[(size_t)node * 64 + ch] = __float2half(ac2[r]);
      }
      float v = acN[r] + b1v;
      v = v > 0.f ? v : 0.01f * v;
      p0[r] = v * w20;
      p1[r] = v * w21;
      #pragma unroll
      for (int off = 1; off < 16; off <<= 1){
        p0[r] += __shfl_xor(p0[r], off);
        p1[r] += __shfl_xor(p1[r], off);
      }
    }
    if (l15 == 0){
      #pragma unroll
      for (int r = 0; r < 4; ++r){
        redP[wave][quad * 4 + r][0] = p0[r];
        redP[wave][quad * 4 + r][1] = p1[r];
      }
    }
    __syncthreads();
    if (t < 16 && tb + t < n){
      float s0 = redP[0][t][0] + redP[1][t][0] + redP[2][t][0] + redP[3][t][0];
      float s1 = redP[0][t][1] + redP[1][t][1] + redP[2][t][1] + redP[3][t][1];
      outN[(size_t)(tb + t) * 2 + 0] = tanhf(s0 + b20);
      outN[(size_t)(tb + t) * 2 + 1] = tanhf(s1 + b21);
    }
    __syncthreads();
  }
}

// 32 edges per wave-iteration: 8 groups of 8 lanes, each group handles edges
// e, e+8, e+16, e+24 (4x unroll -> 64 gathers in flight per wave).
// Per-edge MLP in packed fp16 (native _Float16 ext-vectors -> v_pk_*):
// pk_fma pre-activation, pk_max leaky, v_dot2_f32_f16 final dot (f32 acc).
// Streams (src/dst/ea/out) use nontemporal hints so they don't evict
// P1/P2 gather lines in L2.
__global__ void k_edge_head(const __half* __restrict__ P1h, const __half* __restrict__ P2h,
                            const int* __restrict__ src, const int* __restrict__ dst,
                            const float* __restrict__ eattr, const float* __restrict__ eoW1,
                            const float* __restrict__ b1, const float* __restrict__ W2,
                            const float* __restrict__ b2, float* __restrict__ out, int E){
  int lane = threadIdx.x & 63;
  int jj = lane & 7, q = lane >> 3;
  int wid = (blockIdx.x * blockDim.x + threadIdx.x) >> 6;
  int nw = (gridDim.x * blockDim.x) >> 6;

  // per-lane weight slice (channels 8jj..8jj+7) packed to half2
  const float* rA  = eoW1 + 8192 + jj * 8;   // ea.x row of eoW1
  const float* rB  = eoW1 + 8256 + jj * 8;   // ea.y row of eoW1
  const float* b1p = b1 + jj * 8;
  const float* w2p = W2 + jj * 8;
  half2_t rah[4], rbh[4], bbh[4], w2h[4];
  #pragma unroll
  for (int k = 0; k < 4; ++k){
    rah[k] = (half2_t){(_Float16)rA[2 * k],  (_Float16)rA[2 * k + 1]};
    rbh[k] = (half2_t){(_Float16)rB[2 * k],  (_Float16)rB[2 * k + 1]};
    bbh[k] = (half2_t){(_Float16)b1p[2 * k], (_Float16)b1p[2 * k + 1]};
    w2h[k] = (half2_t){(_Float16)w2p[2 * k], (_Float16)w2p[2 * k + 1]};
  }
  const half2_t slope2 = {(_Float16)0.01f, (_Float16)0.01f};
  float b2v = b2[0];

  const float4* P1q = (const float4*)P1h;
  const float4* P2q = (const float4*)P2h;
  const float2* eav = (const float2*)eattr;

  int groups = (E + 31) >> 5;
  for (int g = wid; g < groups; g += nw){
    int e0 = g * 32 + q;
    float p[4] = {0.f, 0.f, 0.f, 0.f};
    #pragma unroll
    for (int u = 0; u < 4; ++u){
      int e = e0 + u * 8;
      if (e < E){
        int s = __builtin_nontemporal_load(src + e);
        int d = __builtin_nontemporal_load(dst + e);
        float2 ea = ldnt_f2(eav + e);
        float4 g1 = P1q[(size_t)s * 8 + jj];
        float4 g2 = P2q[(size_t)d * 8 + jj];
        const half2_t* h1 = (const half2_t*)&g1;
        const half2_t* h2 = (const half2_t*)&g2;
        _Float16 exs = (_Float16)ea.x, eys = (_Float16)ea.y;
        half2_t ex = {exs, exs};
        half2_t ey = {eys, eys};
        float acc = 0.f;
        #pragma unroll
        for (int k = 0; k < 4; ++k){
          half2_t c = ex * rah[k] + bbh[k];        // v_pk_fma: ea.x*Wx + b1
          c = ey * rbh[k] + c;                     // + ea.y*Wy
          half2_t tv = (h1[k] + h2[k]) + c;        // + P1[s] + P2[d]
          tv = leaky2(tv, slope2);                 // leaky_relu 0.01
          acc = fdot2_acc(tv, w2h[k], acc);        // f32 dot accumulate
        }
        p[u] = acc;
      }
    }
    #pragma unroll
    for (int off = 1; off < 8; off <<= 1){
      #pragma unroll
      for (int u = 0; u < 4; ++u) p[u] += __shfl_xor(p[u], off);
    }
    if (jj == 0){
      #pragma unroll
      for (int u = 0; u < 4; ++u){
        int e = e0 + u * 8;
        if (e < E) __builtin_nontemporal_store(tanhf(p[u] + b2v), out + e);
      }
    }
  }
}

extern "C" void kernel_launch(void* const* d_in, const int* in_sizes, int n_in,
                              void* d_out, int out_size, void* d_ws, size_t ws_size,
                              hipStream_t stream){
  const float* x    = (const float*)d_in[0];
  const int*   eidx = (const int*)  d_in[1];
  const float* ea   = (const float*)d_in[2];
  const float* encW = (const float*)d_in[3];
  const float* encb = (const float*)d_in[4];
  const float* g1W  = (const float*)d_in[5];
  const float* g1as = (const float*)d_in[6];
  const float* g1ad = (const float*)d_in[7];
  const float* g1b  = (const float*)d_in[8];
  const float* g2W  = (const float*)d_in[9];
  const float* g2as = (const float*)d_in[10];
  const float* g2ad = (const float*)d_in[11];
  const float* g2b  = (const float*)d_in[12];
  const float* noW1 = (const float*)d_in[13];
  const float* nob1 = (const float*)d_in[14];
  const float* noW2 = (const float*)d_in[15];
  const float* nob2 = (const float*)d_in[16];
  const float* eoW1 = (const float*)d_in[17];
  const float* eob1 = (const float*)d_in[18];
  const float* eoW2 = (const float*)d_in[19];
  const float* eob2 = (const float*)d_in[20];

  const int N = in_sizes[0] / 2;
  const int E = in_sizes[1] / 2;
  const int* src = eidx;
  const int* dst = eidx + E;

  const int NB = (N + 127) >> 7;         // buckets of 128 nodes (<= 800)
  int avg = (E + NB - 1) / NB;
  int cap = avg + avg / 4 + 64;          // ~25% headroom
  if (cap > 2700) cap = 2700;            // LDS limit in k_bucket_build

  // workspace layout
  char* ws = (char*)d_ws;
  size_t off = 0;
  auto alloc = [&](size_t bytes) -> void* {
    void* p = ws + off;
    off = (off + bytes + 255) & ~(size_t)255;
    return p;
  };
  __half* bufA  = (__half*)alloc((size_t)N * 64 * 2);   // h1 -> h2 (fp16)
  __half* bufH  = (__half*)alloc((size_t)N * 64 * 2);   // hw1 -> hw2
  __half* P1h   = (__half*)alloc((size_t)N * 64 * 2);
  __half* P2h   = (__half*)alloc((size_t)N * 64 * 2);
  float*  as    = (float*) alloc((size_t)N * 4 * 4);
  float*  ad    = (float*) alloc((size_t)N * 4 * 4);
  int2* rowrange = (int2*) alloc((size_t)N * 8);
  unsigned int* ebuf = (unsigned int*)alloc((size_t)NB * cap * 4);   // packed entries
  int* cursor   = (int*)   alloc((size_t)NB * 4);
  float* vsd    = (float*) alloc(128 * 4);              // [g2W@g2as ; g2W@g2ad]

  // ---- CSR build phase 1 + layer-1 hw/alphas + vsd precompute (merged) ----
  hipMemsetAsync(cursor, 0, (size_t)NB * 4, stream);
  k_scatter_fuse<<<(E + 2047) / 2048, 512, 0, stream>>>(
      src, dst, E, NB, cap, cursor, ebuf,
      x, encW, encb, g1W, g1as, g1ad, g2W, g2as, g2ad, vsd, bufH, as, ad, N);
  // ---- CSR build phase 2 (lean sort) ----
  k_bucket_build<<<NB, 256, 0, stream>>>(cursor, cap, N, ebuf, rowrange);
  // ---- layer-1 aggregation + ELU (numerator inline) ----
  k_agg<4, true><<<(N + 3) / 4, 256, 0, stream>>>(bufH, as, ad,
                                                  rowrange, ebuf, g1b, bufA, N);
  // ---- GAT layer 2 (alphas via factored MFMA; numerator inline in agg) ----
  k_hw_mfma<<<(N + 63) / 64, 256, 0, stream>>>(bufA, g2W, vsd, bufH, as, ad, N);
  k_agg<1, false><<<(N + 3) / 4, 256, 0, stream>>>(bufH, as, ad,
                                                   rowrange, ebuf, g2b, bufA, N);
  // ---- heads (fused P1/P2 + node head) ----
  float* out = (float*)d_out;
  k_heads_mfma<<<(N + 63) / 64, 256, 0, stream>>>(bufA, eoW1, noW1, nob1, noW2, nob2,
                                                  P1h, P2h, out + E, N);
  k_edge_head<<<2048, 256, 0, stream>>>(P1h, P2h, src, dst, ea,
                                        eoW1, eob1, eoW2, eob2, out, E);
}

// Round 3
// 356.622 us; speedup vs baseline: 1.0002x; 1.0002x over previous
//
#include <hip/hip_runtime.h>
#include <hip/hip_fp16.h>
#include <math.h>

// ---------------------------------------------------------------------------
// GAT model forward. N=100k nodes, E=1.6M edges, HID=64.
// R19 = R18 minus ALL nontemporal hints in k_edge_head.
// Post-mortem R18: packed fp16 cut VALUBusy 46->30% (confirmed) but nt hints
// grew FETCH 184.5->204.8MB (nt loads don't allocate in L2; the 4x unroll's
// u=0/u=1 instructions share 64B lines of src/dst -> double-fetch) and
// WRITE 6.3->8.4MB (nt partial-line scatter stores). Net neutral.
// R19 keeps the fp16 MLP + 4-edge unroll, restores cached loads/stores.
// ---------------------------------------------------------------------------

typedef _Float16 half8_t __attribute__((ext_vector_type(8)));
typedef _Float16 half2_t __attribute__((ext_vector_type(2)));
typedef float floatx4 __attribute__((ext_vector_type(4)));

#if defined(__has_builtin)
#if __has_builtin(__builtin_amdgcn_fdot2)
#define HAS_FDOT2 1
#endif
#if __has_builtin(__builtin_elementwise_max)
#define HAS_EMAX 1
#endif
#endif

static __device__ __forceinline__ float fdot2_acc(half2_t a, half2_t b, float c){
#ifdef HAS_FDOT2
  return __builtin_amdgcn_fdot2(a, b, c, false);
#else
  return fmaf((float)a[0], (float)b[0], fmaf((float)a[1], (float)b[1], c));
#endif
}

static __device__ __forceinline__ half2_t leaky2(half2_t t, half2_t slope){
#ifdef HAS_EMAX
  return __builtin_elementwise_max(t, t * slope);     // v_pk_max_f16
#else
  half2_t r;
  r[0] = t[0] > (_Float16)0 ? t[0] : t[0] * slope[0];
  r[1] = t[1] > (_Float16)0 ? t[1] : t[1] * slope[1];
  return r;
#endif
}

// Phase 1: bucket edges by dst>>7 (rank trick). Block 0 also computes
// vsd = [g2W@g2as ; g2W@g2ad] for k_hw_mfma's factored alpha MFMA.
// Then grid-stride fuse1 tail: hw1 = fp16(x@Mc+c), H=4 alphas.
// blockDim = 512 (8 waves) for latency-bound occupancy.
__global__ __launch_bounds__(512) void k_scatter_fuse(
    const int* __restrict__ src, const int* __restrict__ dst,
    int E, int NB, int cap, int* cursor,
    unsigned int* __restrict__ ebuf,
    const float* __restrict__ x,
    const float* __restrict__ encW, const float* __restrict__ encb,
    const float* __restrict__ g1W,
    const float* __restrict__ g1as, const float* __restrict__ g1ad,
    const float* __restrict__ g2W,
    const float* __restrict__ g2as, const float* __restrict__ g2ad,
    float* __restrict__ vsd,
    __half* __restrict__ hw, float* __restrict__ alpha_s,
    float* __restrict__ alpha_d, int n){
  __shared__ int hist[800];
  __shared__ int base[800];
  __shared__ float McS[192];
  int t = threadIdx.x;                  // blockDim = 512
  if (t < 64){                          // per-block Mc (g1W is L2-resident)
    float m0 = 0.f, m1 = 0.f, cc = 0.f;
    for (int k = 0; k < 64; ++k){
      float g = g1W[k * 64 + t];
      m0 = fmaf(encW[k], g, m0);
      m1 = fmaf(encW[64 + k], g, m1);
      cc = fmaf(encb[k], g, cc);
    }
    McS[t] = m0; McS[64 + t] = m1; McS[128 + t] = cc;
  }
  if (blockIdx.x == 0 && t >= 64 && t < 128){  // vsd on a different wave
    int k = t - 64;
    float vs = 0.f, vd = 0.f;
    for (int ch = 0; ch < 64; ++ch){
      float g = g2W[k * 64 + ch];
      vs = fmaf(g, g2as[ch], vs);
      vd = fmaf(g, g2ad[ch], vd);
    }
    vsd[k] = vs; vsd[64 + k] = vd;
  }
  for (int i = t; i < NB; i += 512) hist[i] = 0;
  __syncthreads();
  int cbase = blockIdx.x * 2048;
  int sv[4], bk[4], dl[4], rk[4];
  #pragma unroll
  for (int i = 0; i < 4; ++i){
    int e = cbase + i * 512 + t;
    if (e < E){
      int d = dst[e];
      sv[i] = src[e]; bk[i] = d >> 7; dl[i] = d & 127;
      rk[i] = atomicAdd(&hist[bk[i]], 1);   // rank within (block,bucket)
    } else bk[i] = -1;
  }
  __syncthreads();
  for (int i = t; i < NB; i += 512){
    int c = hist[i];
    base[i] = (c > 0) ? (i * cap + atomicAdd(&cursor[i], c)) : 0;
  }
  __syncthreads();
  #pragma unroll
  for (int i = 0; i < 4; ++i){
    if (bk[i] >= 0){
      int p = base[bk[i]] + rk[i];
      if (p < (bk[i] + 1) * cap)        // overflow guard (never fires in practice)
        ebuf[p] = (unsigned)sv[i] | ((unsigned)dl[i] << 17);
    }
  }
  // ---- fuse1 tail: grid-stride over n*64 channels ----
  int total = n * 64;
  int lane = t & 63;
  for (int idx = blockIdx.x * 512 + t; idx < total; idx += gridDim.x * 512){
    int node = idx >> 6;                // j == lane (idx base multiple of 64)
    float acc = fmaf(x[node * 2 + 0], McS[lane],
                fmaf(x[node * 2 + 1], McS[64 + lane], McS[128 + lane]));
    hw[idx] = __float2half(acc);
    float ps = acc * g1as[lane];
    float pd = acc * g1ad[lane];
    #pragma unroll
    for (int off = 1; off < 16; off <<= 1){
      ps += __shfl_xor(ps, off);
      pd += __shfl_xor(pd, off);
    }
    if ((lane & 15) == 0){
      int h = lane >> 4;
      alpha_s[node * 4 + h] = ps;
      alpha_d[node * 4 + h] = pd;
    }
  }
}

// Phase 2: one block (256 thr) per 128-node bucket. Sort in LDS ->
// rowrange (int2) + dst-sorted packed ebuf.
__global__ void k_bucket_build(const int* __restrict__ cursor, int cap, int N,
                               unsigned int* ebuf, int2* __restrict__ rowrange){
  __shared__ unsigned int ent[2700];
  __shared__ unsigned short rank[2700];
  __shared__ int cnts[128];
  __shared__ int aux[128];
  int b = blockIdx.x, t = threadIdx.x;  // blockDim = 256
  int base = b * cap;
  int cnt = cursor[b];
  if (cnt > cap) cnt = cap;
  for (int i = t; i < cnt; i += 256) ent[i] = ebuf[base + i];
  if (t < 128) cnts[t] = 0;
  __syncthreads();
  for (int i = t; i < cnt; i += 256)
    rank[i] = (unsigned short)atomicAdd(&cnts[ent[i] >> 17], 1);
  __syncthreads();
  int v = 0;
  if (t < 128){ v = cnts[t]; aux[t] = v; }
  __syncthreads();
  for (int off = 1; off < 128; off <<= 1){
    int x = 0;
    if (t < 128 && t >= off) x = aux[t - off];
    __syncthreads();
    if (t < 128) aux[t] += x;
    __syncthreads();
  }
  if (t < 128){
    int incl = aux[t];
    int node = (b << 7) + t;
    if (node < N) rowrange[node] = make_int2(base + incl - v, base + incl);
    cnts[t] = incl - v;                 // per-node segment start (no atomics)
  }
  __syncthreads();
  for (int i = t; i < cnt; i += 256){
    unsigned int en = ent[i];
    int pos = cnts[en >> 17] + (int)rank[i];
    ebuf[base + pos] = en;              // keep packed (src|dl<<17)
  }
}

// MFMA GEMM: hw2 = fp16(h1 @ g2W); alphas via factored MFMA on wave 0:
// alpha_{s,d}[node] = h1[node,:] . vsd  (B cols [v_s|v_d|0..]).
// Zero barriers, zero LDS.
__global__ __launch_bounds__(256) void k_hw_mfma(
    const __half* __restrict__ hin, const float* __restrict__ W,
    const float* __restrict__ vsd,
    __half* __restrict__ hw, float* __restrict__ alpha_s,
    float* __restrict__ alpha_d, int n){
  int t = threadIdx.x;
  int lane = t & 63, wave = t >> 6;
  int l15 = lane & 15, quad = lane >> 4;
  int ch = wave * 16 + l15;
  half8_t b0, b1;
  #pragma unroll
  for (int j = 0; j < 8; ++j){
    b0[j] = (_Float16)W[(quad * 8 + j) * 64 + ch];
    b1[j] = (_Float16)W[(quad * 8 + j + 32) * 64 + ch];
  }
  half8_t bA0 = {0,0,0,0,0,0,0,0}, bA1 = {0,0,0,0,0,0,0,0};
  if (wave == 0 && l15 < 2){
    const float* v = vsd + l15 * 64;
    #pragma unroll
    for (int j = 0; j < 8; ++j){
      bA0[j] = (_Float16)v[quad * 8 + j];
      bA1[j] = (_Float16)v[quad * 8 + j + 32];
    }
  }
  int base = blockIdx.x * 64;
  for (int it = 0; it < 4; ++it){
    int tb = base + it * 16;
    if (tb >= n) break;
    int arn = tb + l15; if (arn >= n) arn = n - 1;
    const __half* arow = hin + (size_t)arn * 64 + quad * 8;
    half8_t a0 = *(const half8_t*)arow;
    half8_t a1 = *(const half8_t*)(arow + 32);
    floatx4 acc = {0.f, 0.f, 0.f, 0.f};
    acc = __builtin_amdgcn_mfma_f32_16x16x32_f16(a0, b0, acc, 0, 0, 0);
    acc = __builtin_amdgcn_mfma_f32_16x16x32_f16(a1, b1, acc, 0, 0, 0);
    #pragma unroll
    for (int r = 0; r < 4; ++r){
      int node = tb + quad * 4 + r;
      if (node < n) hw[(size_t)node * 64 + ch] = __float2half(acc[r]);
    }
    if (wave == 0){
      floatx4 accA = {0.f, 0.f, 0.f, 0.f};
      accA = __builtin_amdgcn_mfma_f32_16x16x32_f16(a0, bA0, accA, 0, 0, 0);
      accA = __builtin_amdgcn_mfma_f32_16x16x32_f16(a1, bA1, accA, 0, 0, 0);
      if (l15 < 2){
        float* dstp = (l15 == 0) ? alpha_s : alpha_d;
        #pragma unroll
        for (int r = 0; r < 4; ++r){
          int node = tb + quad * 4 + r;
          if (node < n) dstp[node] = accA[r];
        }
      }
    }
  }
}

// Wave = 1 destination node, 8 edge-groups x 8 lanes; lane jj owns channels
// 8jj..8jj+7 (one 16B fp16 load per edge). Numerator computed in-loop from
// the L2-resident alpha tables. [R8 gather structure: best measured.]
template<int H, bool ELU_ACT>
__global__ void k_agg(const __half* __restrict__ hw,
                      const float* __restrict__ alpha_s, const float* __restrict__ alpha_d,
                      const int2* __restrict__ rowrange,
                      const unsigned int* __restrict__ ebuf,
                      const float* __restrict__ bias, __half* __restrict__ hout, int n){
  int node = (blockIdx.x * blockDim.x + threadIdx.x) >> 6;
  int lane = threadIdx.x & 63;
  int g = lane >> 3, jj = lane & 7;
  if (node >= n) return;
  int hidx = (jj * H) >> 3;                // head of channels 8jj..8jj+7
  int2 rr = rowrange[node];
  int start = rr.x, end = rr.y;
  float adn = alpha_d[node * H + hidx];
  float acc[8] = {0.f,0.f,0.f,0.f,0.f,0.f,0.f,0.f};
  float psum = 0.f;
  if (g == 0){                             // self loop (group 0 only)
    float a = alpha_s[node * H + hidx] + adn;
    a = a > 0.f ? a : 0.2f * a;
    float p = __expf(a);
    psum = p;
    float4 rv = *(const float4*)(hw + (size_t)node * 64 + jj * 8);
    const __half2* hp = (const __half2*)&rv;
    #pragma unroll
    for (int k = 0; k < 4; ++k){
      float2 f = __half22float2(hp[k]);
      acc[2 * k] = p * f.x; acc[2 * k + 1] = p * f.y;
    }
  }
  int i = start + g;
  for (; i + 8 < end; i += 16){
    unsigned int e0 = ebuf[i], e1 = ebuf[i + 8];
    int s0 = e0 & 0x1FFFF, s1 = e1 & 0x1FFFF;
    float a0 = alpha_s[s0 * H + hidx] + adn;
    float a1 = alpha_s[s1 * H + hidx] + adn;
    a0 = a0 > 0.f ? a0 : 0.2f * a0;
    a1 = a1 > 0.f ? a1 : 0.2f * a1;
    float p0 = __expf(a0), p1 = __expf(a1);
    float4 r0 = *(const float4*)(hw + (size_t)s0 * 64 + jj * 8);
    float4 r1 = *(const float4*)(hw + (size_t)s1 * 64 + jj * 8);
    const __half2* h0 = (const __half2*)&r0;
    const __half2* h1 = (const __half2*)&r1;
    psum += p0 + p1;
    #pragma unroll
    for (int k = 0; k < 4; ++k){
      float2 f0 = __half22float2(h0[k]);
      float2 f1 = __half22float2(h1[k]);
      acc[2 * k]     = fmaf(p0, f0.x, fmaf(p1, f1.x, acc[2 * k]));
      acc[2 * k + 1] = fmaf(p0, f0.y, fmaf(p1, f1.y, acc[2 * k + 1]));
    }
  }
  if (i < end){
    unsigned int en = ebuf[i];
    int s = en & 0x1FFFF;
    float a = alpha_s[s * H + hidx] + adn;
    a = a > 0.f ? a : 0.2f * a;
    float p = __expf(a);
    float4 rv = *(const float4*)(hw + (size_t)s * 64 + jj * 8);
    const __half2* hp = (const __half2*)&rv;
    psum += p;
    #pragma unroll
    for (int k = 0; k < 4; ++k){
      float2 f = __half22float2(hp[k]);
      acc[2 * k]     = fmaf(p, f.x, acc[2 * k]);
      acc[2 * k + 1] = fmaf(p, f.y, acc[2 * k + 1]);
    }
  }
  #pragma unroll
  for (int off = 8; off < 64; off <<= 1){
    psum += __shfl_xor(psum, off);
    #pragma unroll
    for (int k = 0; k < 8; ++k) acc[k] += __shfl_xor(acc[k], off);
  }
  if (g == 0){
    float inv = 1.f / (psum + 1e-16f);
    float4 bv0 = ((const float4*)bias)[2 * jj];
    float4 bv1 = ((const float4*)bias)[2 * jj + 1];
    float o[8];
    o[0] = fmaf(acc[0], inv, bv0.x); o[1] = fmaf(acc[1], inv, bv0.y);
    o[2] = fmaf(acc[2], inv, bv0.z); o[3] = fmaf(acc[3], inv, bv0.w);
    o[4] = fmaf(acc[4], inv, bv1.x); o[5] = fmaf(acc[5], inv, bv1.y);
    o[6] = fmaf(acc[6], inv, bv1.z); o[7] = fmaf(acc[7], inv, bv1.w);
    if (ELU_ACT){
      #pragma unroll
      for (int k = 0; k < 8; ++k) o[k] = o[k] > 0.f ? o[k] : (__expf(o[k]) - 1.f);
    }
    half8_t hv;
    #pragma unroll
    for (int k = 0; k < 8; ++k) hv[k] = (_Float16)o[k];
    *(half8_t*)(hout + (size_t)node * 64 + jj * 8) = hv;
  }
}

// Fused heads GEMMs over h2 (fp16): P1/P2 fp16 + node head, 6 MFMAs/wave-tile.
__global__ __launch_bounds__(256) void k_heads_mfma(
    const __half* __restrict__ h, const float* __restrict__ eoW1,
    const float* __restrict__ noW1, const float* __restrict__ nob1,
    const float* __restrict__ noW2, const float* __restrict__ nob2,
    __half* __restrict__ P1, __half* __restrict__ P2,
    float* __restrict__ outN, int n){
  __shared__ float redP[4][16][2];
  int t = threadIdx.x;
  int lane = t & 63, wave = t >> 6;
  int l15 = lane & 15, quad = lane >> 4;
  int ch = wave * 16 + l15;
  half8_t bP1a, bP1b, bP2a, bP2b, bNa, bNb;
  #pragma unroll
  for (int j = 0; j < 8; ++j){
    int k0 = quad * 8 + j, k1 = k0 + 32;
    bP1a[j] = (_Float16)eoW1[k0 * 64 + ch];
    bP1b[j] = (_Float16)eoW1[k1 * 64 + ch];
    bP2a[j] = (_Float16)eoW1[(k0 + 64) * 64 + ch];
    bP2b[j] = (_Float16)eoW1[(k1 + 64) * 64 + ch];
    bNa[j]  = (_Float16)noW1[k0 * 64 + ch];
    bNb[j]  = (_Float16)noW1[k1 * 64 + ch];
  }
  float b1v = nob1[ch];
  float w20 = noW2[ch * 2 + 0], w21 = noW2[ch * 2 + 1];
  float b20 = nob2[0], b21 = nob2[1];
  int base = blockIdx.x * 64;
  for (int it = 0; it < 4; ++it){
    int tb = base + it * 16;
    if (tb >= n) break;
    int arn = tb + l15; if (arn >= n) arn = n - 1;
    const __half* arow = h + (size_t)arn * 64 + quad * 8;
    half8_t a0 = *(const half8_t*)arow;
    half8_t a1 = *(const half8_t*)(arow + 32);
    floatx4 ac1 = {0.f,0.f,0.f,0.f}, ac2 = {0.f,0.f,0.f,0.f}, acN = {0.f,0.f,0.f,0.f};
    ac1 = __builtin_amdgcn_mfma_f32_16x16x32_f16(a0, bP1a, ac1, 0, 0, 0);
    ac1 = __builtin_amdgcn_mfma_f32_16x16x32_f16(a1, bP1b, ac1, 0, 0, 0);
    ac2 = __builtin_amdgcn_mfma_f32_16x16x32_f16(a0, bP2a, ac2, 0, 0, 0);
    ac2 = __builtin_amdgcn_mfma_f32_16x16x32_f16(a1, bP2b, ac2, 0, 0, 0);
    acN = __builtin_amdgcn_mfma_f32_16x16x32_f16(a0, bNa, acN, 0, 0, 0);
    acN = __builtin_amdgcn_mfma_f32_16x16x32_f16(a1, bNb, acN, 0, 0, 0);
    float p0[4], p1[4];
    #pragma unroll
    for (int r = 0; r < 4; ++r){
      int node = tb + quad * 4 + r;
      if (node < n){
        P1[(size_t)node * 64 + ch] = __float2half(ac1[r]);
        P2[(size_t)node * 64 + ch] = __float2half(ac2[r]);
      }
      float v = acN[r] + b1v;
      v = v > 0.f ? v : 0.01f * v;
      p0[r] = v * w20;
      p1[r] = v * w21;
      #pragma unroll
      for (int off = 1; off < 16; off <<= 1){
        p0[r] += __shfl_xor(p0[r], off);
        p1[r] += __shfl_xor(p1[r], off);
      }
    }
    if (l15 == 0){
      #pragma unroll
      for (int r = 0; r < 4; ++r){
        redP[wave][quad * 4 + r][0] = p0[r];
        redP[wave][quad * 4 + r][1] = p1[r];
      }
    }
    __syncthreads();
    if (t < 16 && tb + t < n){
      float s0 = redP[0][t][0] + redP[1][t][0] + redP[2][t][0] + redP[3][t][0];
      float s1 = redP[0][t][1] + redP[1][t][1] + redP[2][t][1] + redP[3][t][1];
      outN[(size_t)(tb + t) * 2 + 0] = tanhf(s0 + b20);
      outN[(size_t)(tb + t) * 2 + 1] = tanhf(s1 + b21);
    }
    __syncthreads();
  }
}

// 32 edges per wave-iteration: 8 groups of 8 lanes, each group handles edges
// e, e+8, e+16, e+24 (4x unroll -> 64 gathers in flight per wave).
// Per-edge MLP in packed fp16 (native _Float16 ext-vectors -> v_pk_*):
// pk_fma pre-activation, pk_max leaky, v_dot2_f32_f16 final dot (f32 acc).
// Plain cached loads/stores (R18's nt hints grew HBM traffic +22MB).
__global__ void k_edge_head(const __half* __restrict__ P1h, const __half* __restrict__ P2h,
                            const int* __restrict__ src, const int* __restrict__ dst,
                            const float* __restrict__ eattr, const float* __restrict__ eoW1,
                            const float* __restrict__ b1, const float* __restrict__ W2,
                            const float* __restrict__ b2, float* __restrict__ out, int E){
  int lane = threadIdx.x & 63;
  int jj = lane & 7, q = lane >> 3;
  int wid = (blockIdx.x * blockDim.x + threadIdx.x) >> 6;
  int nw = (gridDim.x * blockDim.x) >> 6;

  // per-lane weight slice (channels 8jj..8jj+7) packed to half2
  const float* rA  = eoW1 + 8192 + jj * 8;   // ea.x row of eoW1
  const float* rB  = eoW1 + 8256 + jj * 8;   // ea.y row of eoW1
  const float* b1p = b1 + jj * 8;
  const float* w2p = W2 + jj * 8;
  half2_t rah[4], rbh[4], bbh[4], w2h[4];
  #pragma unroll
  for (int k = 0; k < 4; ++k){
    rah[k] = (half2_t){(_Float16)rA[2 * k],  (_Float16)rA[2 * k + 1]};
    rbh[k] = (half2_t){(_Float16)rB[2 * k],  (_Float16)rB[2 * k + 1]};
    bbh[k] = (half2_t){(_Float16)b1p[2 * k], (_Float16)b1p[2 * k + 1]};
    w2h[k] = (half2_t){(_Float16)w2p[2 * k], (_Float16)w2p[2 * k + 1]};
  }
  const half2_t slope2 = {(_Float16)0.01f, (_Float16)0.01f};
  float b2v = b2[0];

  const float4* P1q = (const float4*)P1h;
  const float4* P2q = (const float4*)P2h;
  const float2* eav = (const float2*)eattr;

  int groups = (E + 31) >> 5;
  for (int g = wid; g < groups; g += nw){
    int e0 = g * 32 + q;
    float p[4] = {0.f, 0.f, 0.f, 0.f};
    #pragma unroll
    for (int u = 0; u < 4; ++u){
      int e = e0 + u * 8;
      if (e < E){
        int s = src[e];
        int d = dst[e];
        float2 ea = eav[e];
        float4 g1 = P1q[(size_t)s * 8 + jj];
        float4 g2 = P2q[(size_t)d * 8 + jj];
        const half2_t* h1 = (const half2_t*)&g1;
        const half2_t* h2 = (const half2_t*)&g2;
        _Float16 exs = (_Float16)ea.x, eys = (_Float16)ea.y;
        half2_t ex = {exs, exs};
        half2_t ey = {eys, eys};
        float acc = 0.f;
        #pragma unroll
        for (int k = 0; k < 4; ++k){
          half2_t c = ex * rah[k] + bbh[k];        // v_pk_fma: ea.x*Wx + b1
          c = ey * rbh[k] + c;                     // + ea.y*Wy
          half2_t tv = (h1[k] + h2[k]) + c;        // + P1[s] + P2[d]
          tv = leaky2(tv, slope2);                 // leaky_relu 0.01
          acc = fdot2_acc(tv, w2h[k], acc);        // f32 dot accumulate
        }
        p[u] = acc;
      }
    }
    #pragma unroll
    for (int off = 1; off < 8; off <<= 1){
      #pragma unroll
      for (int u = 0; u < 4; ++u) p[u] += __shfl_xor(p[u], off);
    }
    if (jj == 0){
      #pragma unroll
      for (int u = 0; u < 4; ++u){
        int e = e0 + u * 8;
        if (e < E) out[e] = tanhf(p[u] + b2v);
      }
    }
  }
}

extern "C" void kernel_launch(void* const* d_in, const int* in_sizes, int n_in,
                              void* d_out, int out_size, void* d_ws, size_t ws_size,
                              hipStream_t stream){
  const float* x    = (const float*)d_in[0];
  const int*   eidx = (const int*)  d_in[1];
  const float* ea   = (const float*)d_in[2];
  const float* encW = (const float*)d_in[3];
  const float* encb = (const float*)d_in[4];
  const float* g1W  = (const float*)d_in[5];
  const float* g1as = (const float*)d_in[6];
  const float* g1ad = (const float*)d_in[7];
  const float* g1b  = (const float*)d_in[8];
  const float* g2W  = (const float*)d_in[9];
  const float* g2as = (const float*)d_in[10];
  const float* g2ad = (const float*)d_in[11];
  const float* g2b  = (const float*)d_in[12];
  const float* noW1 = (const float*)d_in[13];
  const float* nob1 = (const float*)d_in[14];
  const float* noW2 = (const float*)d_in[15];
  const float* nob2 = (const float*)d_in[16];
  const float* eoW1 = (const float*)d_in[17];
  const float* eob1 = (const float*)d_in[18];
  const float* eoW2 = (const float*)d_in[19];
  const float* eob2 = (const float*)d_in[20];

  const int N = in_sizes[0] / 2;
  const int E = in_sizes[1] / 2;
  const int* src = eidx;
  const int* dst = eidx + E;

  const int NB = (N + 127) >> 7;         // buckets of 128 nodes (<= 800)
  int avg = (E + NB - 1) / NB;
  int cap = avg + avg / 4 + 64;          // ~25% headroom
  if (cap > 2700) cap = 2700;            // LDS limit in k_bucket_build

  // workspace layout
  char* ws = (char*)d_ws;
  size_t off = 0;
  auto alloc = [&](size_t bytes) -> void* {
    void* p = ws + off;
    off = (off + bytes + 255) & ~(size_t)255;
    return p;
  };
  __half* bufA  = (__half*)alloc((size_t)N * 64 * 2);   // h1 -> h2 (fp16)
  __half* bufH  = (__half*)alloc((size_t)N * 64 * 2);   // hw1 -> hw2
  __half* P1h   = (__half*)alloc((size_t)N * 64 * 2);
  __half* P2h   = (__half*)alloc((size_t)N * 64 * 2);
  float*  as    = (float*) alloc((size_t)N * 4 * 4);
  float*  ad    = (float*) alloc((size_t)N * 4 * 4);
  int2* rowrange = (int2*) alloc((size_t)N * 8);
  unsigned int* ebuf = (unsigned int*)alloc((size_t)NB * cap * 4);   // packed entries
  int* cursor   = (int*)   alloc((size_t)NB * 4);
  float* vsd    = (float*) alloc(128 * 4);              // [g2W@g2as ; g2W@g2ad]

  // ---- CSR build phase 1 + layer-1 hw/alphas + vsd precompute (merged) ----
  hipMemsetAsync(cursor, 0, (size_t)NB * 4, stream);
  k_scatter_fuse<<<(E + 2047) / 2048, 512, 0, stream>>>(
      src, dst, E, NB, cap, cursor, ebuf,
      x, encW, encb, g1W, g1as, g1ad, g2W, g2as, g2ad, vsd, bufH, as, ad, N);
  // ---- CSR build phase 2 (lean sort) ----
  k_bucket_build<<<NB, 256, 0, stream>>>(cursor, cap, N, ebuf, rowrange);
  // ---- layer-1 aggregation + ELU (numerator inline) ----
  k_agg<4, true><<<(N + 3) / 4, 256, 0, stream>>>(bufH, as, ad,
                                                  rowrange, ebuf, g1b, bufA, N);
  // ---- GAT layer 2 (alphas via factored MFMA; numerator inline in agg) ----
  k_hw_mfma<<<(N + 63) / 64, 256, 0, stream>>>(bufA, g2W, vsd, bufH, as, ad, N);
  k_agg<1, false><<<(N + 3) / 4, 256, 0, stream>>>(bufH, as, ad,
                                                   rowrange, ebuf, g2b, bufA, N);
  // ---- heads (fused P1/P2 + node head) ----
  float* out = (float*)d_out;
  k_heads_mfma<<<(N + 63) / 64, 256, 0, stream>>>(bufA, eoW1, noW1, nob1, noW2, nob2,
                                                  P1h, P2h, out + E, N);
  k_edge_head<<<2048, 256, 0, stream>>>(P1h, P2h, src, dst, ea,
                                        eoW1, eob1, eoW2, eob2, out, E);
}

// Round 4
// 351.472 us; speedup vs baseline: 1.0149x; 1.0147x over previous
//
#include <hip/hip_runtime.h>
#include <hip/hip_fp16.h>
#include <math.h>

// ---------------------------------------------------------------------------
// GAT model forward. N=100k nodes, E=1.6M edges, HID=64.
// R20 = R19 with k_edge_head unrolled 4 -> 8 edges per 8-lane group.
// R19 post-mortem: fp16 MLP cut VALU 46->33%, rate 3.15->3.40 TB/s, but
// nothing saturated (HBM 42%, occupancy 76%, VGPR 24) -> still latency-bound
// on the dependent chain src[e] -> P1/P2 gather with only 4 pairs in flight.
// 8x unroll doubles gathers in flight (16/group, 128/wave); VGPR headroom
// (24 -> ~100) absorbs it. Everything else byte-identical to R19.
// ---------------------------------------------------------------------------

typedef _Float16 half8_t __attribute__((ext_vector_type(8)));
typedef _Float16 half2_t __attribute__((ext_vector_type(2)));
typedef float floatx4 __attribute__((ext_vector_type(4)));

#if defined(__has_builtin)
#if __has_builtin(__builtin_amdgcn_fdot2)
#define HAS_FDOT2 1
#endif
#if __has_builtin(__builtin_elementwise_max)
#define HAS_EMAX 1
#endif
#endif

static __device__ __forceinline__ float fdot2_acc(half2_t a, half2_t b, float c){
#ifdef HAS_FDOT2
  return __builtin_amdgcn_fdot2(a, b, c, false);
#else
  return fmaf((float)a[0], (float)b[0], fmaf((float)a[1], (float)b[1], c));
#endif
}

static __device__ __forceinline__ half2_t leaky2(half2_t t, half2_t slope){
#ifdef HAS_EMAX
  return __builtin_elementwise_max(t, t * slope);     // v_pk_max_f16
#else
  half2_t r;
  r[0] = t[0] > (_Float16)0 ? t[0] : t[0] * slope[0];
  r[1] = t[1] > (_Float16)0 ? t[1] : t[1] * slope[1];
  return r;
#endif
}

// Phase 1: bucket edges by dst>>7 (rank trick). Block 0 also computes
// vsd = [g2W@g2as ; g2W@g2ad] for k_hw_mfma's factored alpha MFMA.
// Then grid-stride fuse1 tail: hw1 = fp16(x@Mc+c), H=4 alphas.
// blockDim = 512 (8 waves) for latency-bound occupancy.
__global__ __launch_bounds__(512) void k_scatter_fuse(
    const int* __restrict__ src, const int* __restrict__ dst,
    int E, int NB, int cap, int* cursor,
    unsigned int* __restrict__ ebuf,
    const float* __restrict__ x,
    const float* __restrict__ encW, const float* __restrict__ encb,
    const float* __restrict__ g1W,
    const float* __restrict__ g1as, const float* __restrict__ g1ad,
    const float* __restrict__ g2W,
    const float* __restrict__ g2as, const float* __restrict__ g2ad,
    float* __restrict__ vsd,
    __half* __restrict__ hw, float* __restrict__ alpha_s,
    float* __restrict__ alpha_d, int n){
  __shared__ int hist[800];
  __shared__ int base[800];
  __shared__ float McS[192];
  int t = threadIdx.x;                  // blockDim = 512
  if (t < 64){                          // per-block Mc (g1W is L2-resident)
    float m0 = 0.f, m1 = 0.f, cc = 0.f;
    for (int k = 0; k < 64; ++k){
      float g = g1W[k * 64 + t];
      m0 = fmaf(encW[k], g, m0);
      m1 = fmaf(encW[64 + k], g, m1);
      cc = fmaf(encb[k], g, cc);
    }
    McS[t] = m0; McS[64 + t] = m1; McS[128 + t] = cc;
  }
  if (blockIdx.x == 0 && t >= 64 && t < 128){  // vsd on a different wave
    int k = t - 64;
    float vs = 0.f, vd = 0.f;
    for (int ch = 0; ch < 64; ++ch){
      float g = g2W[k * 64 + ch];
      vs = fmaf(g, g2as[ch], vs);
      vd = fmaf(g, g2ad[ch], vd);
    }
    vsd[k] = vs; vsd[64 + k] = vd;
  }
  for (int i = t; i < NB; i += 512) hist[i] = 0;
  __syncthreads();
  int cbase = blockIdx.x * 2048;
  int sv[4], bk[4], dl[4], rk[4];
  #pragma unroll
  for (int i = 0; i < 4; ++i){
    int e = cbase + i * 512 + t;
    if (e < E){
      int d = dst[e];
      sv[i] = src[e]; bk[i] = d >> 7; dl[i] = d & 127;
      rk[i] = atomicAdd(&hist[bk[i]], 1);   // rank within (block,bucket)
    } else bk[i] = -1;
  }
  __syncthreads();
  for (int i = t; i < NB; i += 512){
    int c = hist[i];
    base[i] = (c > 0) ? (i * cap + atomicAdd(&cursor[i], c)) : 0;
  }
  __syncthreads();
  #pragma unroll
  for (int i = 0; i < 4; ++i){
    if (bk[i] >= 0){
      int p = base[bk[i]] + rk[i];
      if (p < (bk[i] + 1) * cap)        // overflow guard (never fires in practice)
        ebuf[p] = (unsigned)sv[i] | ((unsigned)dl[i] << 17);
    }
  }
  // ---- fuse1 tail: grid-stride over n*64 channels ----
  int total = n * 64;
  int lane = t & 63;
  for (int idx = blockIdx.x * 512 + t; idx < total; idx += gridDim.x * 512){
    int node = idx >> 6;                // j == lane (idx base multiple of 64)
    float acc = fmaf(x[node * 2 + 0], McS[lane],
                fmaf(x[node * 2 + 1], McS[64 + lane], McS[128 + lane]));
    hw[idx] = __float2half(acc);
    float ps = acc * g1as[lane];
    float pd = acc * g1ad[lane];
    #pragma unroll
    for (int off = 1; off < 16; off <<= 1){
      ps += __shfl_xor(ps, off);
      pd += __shfl_xor(pd, off);
    }
    if ((lane & 15) == 0){
      int h = lane >> 4;
      alpha_s[node * 4 + h] = ps;
      alpha_d[node * 4 + h] = pd;
    }
  }
}

// Phase 2: one block (256 thr) per 128-node bucket. Sort in LDS ->
// rowrange (int2) + dst-sorted packed ebuf.
__global__ void k_bucket_build(const int* __restrict__ cursor, int cap, int N,
                               unsigned int* ebuf, int2* __restrict__ rowrange){
  __shared__ unsigned int ent[2700];
  __shared__ unsigned short rank[2700];
  __shared__ int cnts[128];
  __shared__ int aux[128];
  int b = blockIdx.x, t = threadIdx.x;  // blockDim = 256
  int base = b * cap;
  int cnt = cursor[b];
  if (cnt > cap) cnt = cap;
  for (int i = t; i < cnt; i += 256) ent[i] = ebuf[base + i];
  if (t < 128) cnts[t] = 0;
  __syncthreads();
  for (int i = t; i < cnt; i += 256)
    rank[i] = (unsigned short)atomicAdd(&cnts[ent[i] >> 17], 1);
  __syncthreads();
  int v = 0;
  if (t < 128){ v = cnts[t]; aux[t] = v; }
  __syncthreads();
  for (int off = 1; off < 128; off <<= 1){
    int x = 0;
    if (t < 128 && t >= off) x = aux[t - off];
    __syncthreads();
    if (t < 128) aux[t] += x;
    __syncthreads();
  }
  if (t < 128){
    int incl = aux[t];
    int node = (b << 7) + t;
    if (node < N) rowrange[node] = make_int2(base + incl - v, base + incl);
    cnts[t] = incl - v;                 // per-node segment start (no atomics)
  }
  __syncthreads();
  for (int i = t; i < cnt; i += 256){
    unsigned int en = ent[i];
    int pos = cnts[en >> 17] + (int)rank[i];
    ebuf[base + pos] = en;              // keep packed (src|dl<<17)
  }
}

// MFMA GEMM: hw2 = fp16(h1 @ g2W); alphas via factored MFMA on wave 0:
// alpha_{s,d}[node] = h1[node,:] . vsd  (B cols [v_s|v_d|0..]).
// Zero barriers, zero LDS.
__global__ __launch_bounds__(256) void k_hw_mfma(
    const __half* __restrict__ hin, const float* __restrict__ W,
    const float* __restrict__ vsd,
    __half* __restrict__ hw, float* __restrict__ alpha_s,
    float* __restrict__ alpha_d, int n){
  int t = threadIdx.x;
  int lane = t & 63, wave = t >> 6;
  int l15 = lane & 15, quad = lane >> 4;
  int ch = wave * 16 + l15;
  half8_t b0, b1;
  #pragma unroll
  for (int j = 0; j < 8; ++j){
    b0[j] = (_Float16)W[(quad * 8 + j) * 64 + ch];
    b1[j] = (_Float16)W[(quad * 8 + j + 32) * 64 + ch];
  }
  half8_t bA0 = {0,0,0,0,0,0,0,0}, bA1 = {0,0,0,0,0,0,0,0};
  if (wave == 0 && l15 < 2){
    const float* v = vsd + l15 * 64;
    #pragma unroll
    for (int j = 0; j < 8; ++j){
      bA0[j] = (_Float16)v[quad * 8 + j];
      bA1[j] = (_Float16)v[quad * 8 + j + 32];
    }
  }
  int base = blockIdx.x * 64;
  for (int it = 0; it < 4; ++it){
    int tb = base + it * 16;
    if (tb >= n) break;
    int arn = tb + l15; if (arn >= n) arn = n - 1;
    const __half* arow = hin + (size_t)arn * 64 + quad * 8;
    half8_t a0 = *(const half8_t*)arow;
    half8_t a1 = *(const half8_t*)(arow + 32);
    floatx4 acc = {0.f, 0.f, 0.f, 0.f};
    acc = __builtin_amdgcn_mfma_f32_16x16x32_f16(a0, b0, acc, 0, 0, 0);
    acc = __builtin_amdgcn_mfma_f32_16x16x32_f16(a1, b1, acc, 0, 0, 0);
    #pragma unroll
    for (int r = 0; r < 4; ++r){
      int node = tb + quad * 4 + r;
      if (node < n) hw[(size_t)node * 64 + ch] = __float2half(acc[r]);
    }
    if (wave == 0){
      floatx4 accA = {0.f, 0.f, 0.f, 0.f};
      accA = __builtin_amdgcn_mfma_f32_16x16x32_f16(a0, bA0, accA, 0, 0, 0);
      accA = __builtin_amdgcn_mfma_f32_16x16x32_f16(a1, bA1, accA, 0, 0, 0);
      if (l15 < 2){
        float* dstp = (l15 == 0) ? alpha_s : alpha_d;
        #pragma unroll
        for (int r = 0; r < 4; ++r){
          int node = tb + quad * 4 + r;
          if (node < n) dstp[node] = accA[r];
        }
      }
    }
  }
}

// Wave = 1 destination node, 8 edge-groups x 8 lanes; lane jj owns channels
// 8jj..8jj+7 (one 16B fp16 load per edge). Numerator computed in-loop from
// the L2-resident alpha tables. [R8 gather structure: best measured.]
template<int H, bool ELU_ACT>
__global__ void k_agg(const __half* __restrict__ hw,
                      const float* __restrict__ alpha_s, const float* __restrict__ alpha_d,
                      const int2* __restrict__ rowrange,
                      const unsigned int* __restrict__ ebuf,
                      const float* __restrict__ bias, __half* __restrict__ hout, int n){
  int node = (blockIdx.x * blockDim.x + threadIdx.x) >> 6;
  int lane = threadIdx.x & 63;
  int g = lane >> 3, jj = lane & 7;
  if (node >= n) return;
  int hidx = (jj * H) >> 3;                // head of channels 8jj..8jj+7
  int2 rr = rowrange[node];
  int start = rr.x, end = rr.y;
  float adn = alpha_d[node * H + hidx];
  float acc[8] = {0.f,0.f,0.f,0.f,0.f,0.f,0.f,0.f};
  float psum = 0.f;
  if (g == 0){                             // self loop (group 0 only)
    float a = alpha_s[node * H + hidx] + adn;
    a = a > 0.f ? a : 0.2f * a;
    float p = __expf(a);
    psum = p;
    float4 rv = *(const float4*)(hw + (size_t)node * 64 + jj * 8);
    const __half2* hp = (const __half2*)&rv;
    #pragma unroll
    for (int k = 0; k < 4; ++k){
      float2 f = __half22float2(hp[k]);
      acc[2 * k] = p * f.x; acc[2 * k + 1] = p * f.y;
    }
  }
  int i = start + g;
  for (; i + 8 < end; i += 16){
    unsigned int e0 = ebuf[i], e1 = ebuf[i + 8];
    int s0 = e0 & 0x1FFFF, s1 = e1 & 0x1FFFF;
    float a0 = alpha_s[s0 * H + hidx] + adn;
    float a1 = alpha_s[s1 * H + hidx] + adn;
    a0 = a0 > 0.f ? a0 : 0.2f * a0;
    a1 = a1 > 0.f ? a1 : 0.2f * a1;
    float p0 = __expf(a0), p1 = __expf(a1);
    float4 r0 = *(const float4*)(hw + (size_t)s0 * 64 + jj * 8);
    float4 r1 = *(const float4*)(hw + (size_t)s1 * 64 + jj * 8);
    const __half2* h0 = (const __half2*)&r0;
    const __half2* h1 = (const __half2*)&r1;
    psum += p0 + p1;
    #pragma unroll
    for (int k = 0; k < 4; ++k){
      float2 f0 = __half22float2(h0[k]);
      float2 f1 = __half22float2(h1[k]);
      acc[2 * k]     = fmaf(p0, f0.x, fmaf(p1, f1.x, acc[2 * k]));
      acc[2 * k + 1] = fmaf(p0, f0.y, fmaf(p1, f1.y, acc[2 * k + 1]));
    }
  }
  if (i < end){
    unsigned int en = ebuf[i];
    int s = en & 0x1FFFF;
    float a = alpha_s[s * H + hidx] + adn;
    a = a > 0.f ? a : 0.2f * a;
    float p = __expf(a);
    float4 rv = *(const float4*)(hw + (size_t)s * 64 + jj * 8);
    const __half2* hp = (const __half2*)&rv;
    psum += p;
    #pragma unroll
    for (int k = 0; k < 4; ++k){
      float2 f = __half22float2(hp[k]);
      acc[2 * k]     = fmaf(p, f.x, acc[2 * k]);
      acc[2 * k + 1] = fmaf(p, f.y, acc[2 * k + 1]);
    }
  }
  #pragma unroll
  for (int off = 8; off < 64; off <<= 1){
    psum += __shfl_xor(psum, off);
    #pragma unroll
    for (int k = 0; k < 8; ++k) acc[k] += __shfl_xor(acc[k], off);
  }
  if (g == 0){
    float inv = 1.f / (psum + 1e-16f);
    float4 bv0 = ((const float4*)bias)[2 * jj];
    float4 bv1 = ((const float4*)bias)[2 * jj + 1];
    float o[8];
    o[0] = fmaf(acc[0], inv, bv0.x); o[1] = fmaf(acc[1], inv, bv0.y);
    o[2] = fmaf(acc[2], inv, bv0.z); o[3] = fmaf(acc[3], inv, bv0.w);
    o[4] = fmaf(acc[4], inv, bv1.x); o[5] = fmaf(acc[5], inv, bv1.y);
    o[6] = fmaf(acc[6], inv, bv1.z); o[7] = fmaf(acc[7], inv, bv1.w);
    if (ELU_ACT){
      #pragma unroll
      for (int k = 0; k < 8; ++k) o[k] = o[k] > 0.f ? o[k] : (__expf(o[k]) - 1.f);
    }
    half8_t hv;
    #pragma unroll
    for (int k = 0; k < 8; ++k) hv[k] = (_Float16)o[k];
    *(half8_t*)(hout + (size_t)node * 64 + jj * 8) = hv;
  }
}

// Fused heads GEMMs over h2 (fp16): P1/P2 fp16 + node head, 6 MFMAs/wave-tile.
__global__ __launch_bounds__(256) void k_heads_mfma(
    const __half* __restrict__ h, const float* __restrict__ eoW1,
    const float* __restrict__ noW1, const float* __restrict__ nob1,
    const float* __restrict__ noW2, const float* __restrict__ nob2,
    __half* __restrict__ P1, __half* __restrict__ P2,
    float* __restrict__ outN, int n){
  __shared__ float redP[4][16][2];
  int t = threadIdx.x;
  int lane = t & 63, wave = t >> 6;
  int l15 = lane & 15, quad = lane >> 4;
  int ch = wave * 16 + l15;
  half8_t bP1a, bP1b, bP2a, bP2b, bNa, bNb;
  #pragma unroll
  for (int j = 0; j < 8; ++j){
    int k0 = quad * 8 + j, k1 = k0 + 32;
    bP1a[j] = (_Float16)eoW1[k0 * 64 + ch];
    bP1b[j] = (_Float16)eoW1[k1 * 64 + ch];
    bP2a[j] = (_Float16)eoW1[(k0 + 64) * 64 + ch];
    bP2b[j] = (_Float16)eoW1[(k1 + 64) * 64 + ch];
    bNa[j]  = (_Float16)noW1[k0 * 64 + ch];
    bNb[j]  = (_Float16)noW1[k1 * 64 + ch];
  }
  float b1v = nob1[ch];
  float w20 = noW2[ch * 2 + 0], w21 = noW2[ch * 2 + 1];
  float b20 = nob2[0], b21 = nob2[1];
  int base = blockIdx.x * 64;
  for (int it = 0; it < 4; ++it){
    int tb = base + it * 16;
    if (tb >= n) break;
    int arn = tb + l15; if (arn >= n) arn = n - 1;
    const __half* arow = h + (size_t)arn * 64 + quad * 8;
    half8_t a0 = *(const half8_t*)arow;
    half8_t a1 = *(const half8_t*)(arow + 32);
    floatx4 ac1 = {0.f,0.f,0.f,0.f}, ac2 = {0.f,0.f,0.f,0.f}, acN = {0.f,0.f,0.f,0.f};
    ac1 = __builtin_amdgcn_mfma_f32_16x16x32_f16(a0, bP1a, ac1, 0, 0, 0);
    ac1 = __builtin_amdgcn_mfma_f32_16x16x32_f16(a1, bP1b, ac1, 0, 0, 0);
    ac2 = __builtin_amdgcn_mfma_f32_16x16x32_f16(a0, bP2a, ac2, 0, 0, 0);
    ac2 = __builtin_amdgcn_mfma_f32_16x16x32_f16(a1, bP2b, ac2, 0, 0, 0);
    acN = __builtin_amdgcn_mfma_f32_16x16x32_f16(a0, bNa, acN, 0, 0, 0);
    acN = __builtin_amdgcn_mfma_f32_16x16x32_f16(a1, bNb, acN, 0, 0, 0);
    float p0[4], p1[4];
    #pragma unroll
    for (int r = 0; r < 4; ++r){
      int node = tb + quad * 4 + r;
      if (node < n){
        P1[(size_t)node * 64 + ch] = __float2half(ac1[r]);
        P2[(size_t)node * 64 + ch] = __float2half(ac2[r]);
      }
      float v = acN[r] + b1v;
      v = v > 0.f ? v : 0.01f * v;
      p0[r] = v * w20;
      p1[r] = v * w21;
      #pragma unroll
      for (int off = 1; off < 16; off <<= 1){
        p0[r] += __shfl_xor(p0[r], off);
        p1[r] += __shfl_xor(p1[r], off);
      }
    }
    if (l15 == 0){
      #pragma unroll
      for (int r = 0; r < 4; ++r){
        redP[wave][quad * 4 + r][0] = p0[r];
        redP[wave][quad * 4 + r][1] = p1[r];
      }
    }
    __syncthreads();
    if (t < 16 && tb + t < n){
      float s0 = redP[0][t][0] + redP[1][t][0] + redP[2][t][0] + redP[3][t][0];
      float s1 = redP[0][t][1] + redP[1][t][1] + redP[2][t][1] + redP[3][t][1];
      outN[(size_t)(tb + t) * 2 + 0] = tanhf(s0 + b20);
      outN[(size_t)(tb + t) * 2 + 1] = tanhf(s1 + b21);
    }
    __syncthreads();
  }
}

// 64 edges per wave-iteration: 8 groups of 8 lanes, each group handles edges
// e, e+8, ..., e+56 (8x unroll -> 128 gathers in flight per wave).
// Per-edge MLP in packed fp16 (native _Float16 ext-vectors -> v_pk_*):
// pk_fma pre-activation, pk_max leaky, v_dot2_f32_f16 final dot (f32 acc).
// Plain cached loads/stores (R18's nt hints grew HBM traffic +22MB).
__global__ void k_edge_head(const __half* __restrict__ P1h, const __half* __restrict__ P2h,
                            const int* __restrict__ src, const int* __restrict__ dst,
                            const float* __restrict__ eattr, const float* __restrict__ eoW1,
                            const float* __restrict__ b1, const float* __restrict__ W2,
                            const float* __restrict__ b2, float* __restrict__ out, int E){
  int lane = threadIdx.x & 63;
  int jj = lane & 7, q = lane >> 3;
  int wid = (blockIdx.x * blockDim.x + threadIdx.x) >> 6;
  int nw = (gridDim.x * blockDim.x) >> 6;

  // per-lane weight slice (channels 8jj..8jj+7) packed to half2
  const float* rA  = eoW1 + 8192 + jj * 8;   // ea.x row of eoW1
  const float* rB  = eoW1 + 8256 + jj * 8;   // ea.y row of eoW1
  const float* b1p = b1 + jj * 8;
  const float* w2p = W2 + jj * 8;
  half2_t rah[4], rbh[4], bbh[4], w2h[4];
  #pragma unroll
  for (int k = 0; k < 4; ++k){
    rah[k] = (half2_t){(_Float16)rA[2 * k],  (_Float16)rA[2 * k + 1]};
    rbh[k] = (half2_t){(_Float16)rB[2 * k],  (_Float16)rB[2 * k + 1]};
    bbh[k] = (half2_t){(_Float16)b1p[2 * k], (_Float16)b1p[2 * k + 1]};
    w2h[k] = (half2_t){(_Float16)w2p[2 * k], (_Float16)w2p[2 * k + 1]};
  }
  const half2_t slope2 = {(_Float16)0.01f, (_Float16)0.01f};
  float b2v = b2[0];

  const float4* P1q = (const float4*)P1h;
  const float4* P2q = (const float4*)P2h;
  const float2* eav = (const float2*)eattr;

  int groups = (E + 63) >> 6;
  for (int g = wid; g < groups; g += nw){
    int e0 = g * 64 + q;
    float p[8] = {0.f, 0.f, 0.f, 0.f, 0.f, 0.f, 0.f, 0.f};
    #pragma unroll
    for (int u = 0; u < 8; ++u){
      int e = e0 + u * 8;
      if (e < E){
        int s = src[e];
        int d = dst[e];
        float2 ea = eav[e];
        float4 g1 = P1q[(size_t)s * 8 + jj];
        float4 g2 = P2q[(size_t)d * 8 + jj];
        const half2_t* h1 = (const half2_t*)&g1;
        const half2_t* h2 = (const half2_t*)&g2;
        _Float16 exs = (_Float16)ea.x, eys = (_Float16)ea.y;
        half2_t ex = {exs, exs};
        half2_t ey = {eys, eys};
        float acc = 0.f;
        #pragma unroll
        for (int k = 0; k < 4; ++k){
          half2_t c = ex * rah[k] + bbh[k];        // v_pk_fma: ea.x*Wx + b1
          c = ey * rbh[k] + c;                     // + ea.y*Wy
          half2_t tv = (h1[k] + h2[k]) + c;        // + P1[s] + P2[d]
          tv = leaky2(tv, slope2);                 // leaky_relu 0.01
          acc = fdot2_acc(tv, w2h[k], acc);        // f32 dot accumulate
        }
        p[u] = acc;
      }
    }
    #pragma unroll
    for (int off = 1; off < 8; off <<= 1){
      #pragma unroll
      for (int u = 0; u < 8; ++u) p[u] += __shfl_xor(p[u], off);
    }
    if (jj == 0){
      #pragma unroll
      for (int u = 0; u < 8; ++u){
        int e = e0 + u * 8;
        if (e < E) out[e] = tanhf(p[u] + b2v);
      }
    }
  }
}

extern "C" void kernel_launch(void* const* d_in, const int* in_sizes, int n_in,
                              void* d_out, int out_size, void* d_ws, size_t ws_size,
                              hipStream_t stream){
  const float* x    = (const float*)d_in[0];
  const int*   eidx = (const int*)  d_in[1];
  const float* ea   = (const float*)d_in[2];
  const float* encW = (const float*)d_in[3];
  const float* encb = (const float*)d_in[4];
  const float* g1W  = (const float*)d_in[5];
  const float* g1as = (const float*)d_in[6];
  const float* g1ad = (const float*)d_in[7];
  const float* g1b  = (const float*)d_in[8];
  const float* g2W  = (const float*)d_in[9];
  const float* g2as = (const float*)d_in[10];
  const float* g2ad = (const float*)d_in[11];
  const float* g2b  = (const float*)d_in[12];
  const float* noW1 = (const float*)d_in[13];
  const float* nob1 = (const float*)d_in[14];
  const float* noW2 = (const float*)d_in[15];
  const float* nob2 = (const float*)d_in[16];
  const float* eoW1 = (const float*)d_in[17];
  const float* eob1 = (const float*)d_in[18];
  const float* eoW2 = (const float*)d_in[19];
  const float* eob2 = (const float*)d_in[20];

  const int N = in_sizes[0] / 2;
  const int E = in_sizes[1] / 2;
  const int* src = eidx;
  const int* dst = eidx + E;

  const int NB = (N + 127) >> 7;         // buckets of 128 nodes (<= 800)
  int avg = (E + NB - 1) / NB;
  int cap = avg + avg / 4 + 64;          // ~25% headroom
  if (cap > 2700) cap = 2700;            // LDS limit in k_bucket_build

  // workspace layout
  char* ws = (char*)d_ws;
  size_t off = 0;
  auto alloc = [&](size_t bytes) -> void* {
    void* p = ws + off;
    off = (off + bytes + 255) & ~(size_t)255;
    return p;
  };
  __half* bufA  = (__half*)alloc((size_t)N * 64 * 2);   // h1 -> h2 (fp16)
  __half* bufH  = (__half*)alloc((size_t)N * 64 * 2);   // hw1 -> hw2
  __half* P1h   = (__half*)alloc((size_t)N * 64 * 2);
  __half* P2h   = (__half*)alloc((size_t)N * 64 * 2);
  float*  as    = (float*) alloc((size_t)N * 4 * 4);
  float*  ad    = (float*) alloc((size_t)N * 4 * 4);
  int2* rowrange = (int2*) alloc((size_t)N * 8);
  unsigned int* ebuf = (unsigned int*)alloc((size_t)NB * cap * 4);   // packed entries
  int* cursor   = (int*)   alloc((size_t)NB * 4);
  float* vsd    = (float*) alloc(128 * 4);              // [g2W@g2as ; g2W@g2ad]

  // ---- CSR build phase 1 + layer-1 hw/alphas + vsd precompute (merged) ----
  hipMemsetAsync(cursor, 0, (size_t)NB * 4, stream);
  k_scatter_fuse<<<(E + 2047) / 2048, 512, 0, stream>>>(
      src, dst, E, NB, cap, cursor, ebuf,
      x, encW, encb, g1W, g1as, g1ad, g2W, g2as, g2ad, vsd, bufH, as, ad, N);
  // ---- CSR build phase 2 (lean sort) ----
  k_bucket_build<<<NB, 256, 0, stream>>>(cursor, cap, N, ebuf, rowrange);
  // ---- layer-1 aggregation + ELU (numerator inline) ----
  k_agg<4, true><<<(N + 3) / 4, 256, 0, stream>>>(bufH, as, ad,
                                                  rowrange, ebuf, g1b, bufA, N);
  // ---- GAT layer 2 (alphas via factored MFMA; numerator inline in agg) ----
  k_hw_mfma<<<(N + 63) / 64, 256, 0, stream>>>(bufA, g2W, vsd, bufH, as, ad, N);
  k_agg<1, false><<<(N + 3) / 4, 256, 0, stream>>>(bufH, as, ad,
                                                   rowrange, ebuf, g2b, bufA, N);
  // ---- heads (fused P1/P2 + node head) ----
  float* out = (float*)d_out;
  k_heads_mfma<<<(N + 63) / 64, 256, 0, stream>>>(bufA, eoW1, noW1, nob1, noW2, nob2,
                                                  P1h, P2h, out + E, N);
  k_edge_head<<<2048, 256, 0, stream>>>(P1h, P2h, src, dst, ea,
                                        eoW1, eob1, eoW2, eob2, out, E);
}

// Round 5
// 350.292 us; speedup vs baseline: 1.0183x; 1.0034x over previous
//
#include <hip/hip_runtime.h>
#include <hip/hip_fp16.h>
#include <math.h>

// ---------------------------------------------------------------------------
// GAT model forward. N=100k nodes, E=1.6M edges, HID=64.
// R21 = exact R19 (best measured edge_head: 57.8us @ 3.40 TB/s).
// R20 post-mortem: 8x unroll regressed edge_head 57.8->63.2us; VGPR stayed 28
// (predicted ~100) -> compiler register-minimized and serialized the gathers,
// REDUCING loads in flight vs the 4x version. Reverted.
// Evidence ledger for the edge_head structural ceiling (R16-R20):
//   bytes 185MB invariant; rate 3.1-3.4 TB/s invariant across VALU 46->30%,
//   unroll 2/4/8, nt-hint on/off. Random-128B-gather fabric ceiling.
// ---------------------------------------------------------------------------

typedef _Float16 half8_t __attribute__((ext_vector_type(8)));
typedef _Float16 half2_t __attribute__((ext_vector_type(2)));
typedef float floatx4 __attribute__((ext_vector_type(4)));

#if defined(__has_builtin)
#if __has_builtin(__builtin_amdgcn_fdot2)
#define HAS_FDOT2 1
#endif
#if __has_builtin(__builtin_elementwise_max)
#define HAS_EMAX 1
#endif
#endif

static __device__ __forceinline__ float fdot2_acc(half2_t a, half2_t b, float c){
#ifdef HAS_FDOT2
  return __builtin_amdgcn_fdot2(a, b, c, false);
#else
  return fmaf((float)a[0], (float)b[0], fmaf((float)a[1], (float)b[1], c));
#endif
}

static __device__ __forceinline__ half2_t leaky2(half2_t t, half2_t slope){
#ifdef HAS_EMAX
  return __builtin_elementwise_max(t, t * slope);     // v_pk_max_f16
#else
  half2_t r;
  r[0] = t[0] > (_Float16)0 ? t[0] : t[0] * slope[0];
  r[1] = t[1] > (_Float16)0 ? t[1] : t[1] * slope[1];
  return r;
#endif
}

// Phase 1: bucket edges by dst>>7 (rank trick). Block 0 also computes
// vsd = [g2W@g2as ; g2W@g2ad] for k_hw_mfma's factored alpha MFMA.
// Then grid-stride fuse1 tail: hw1 = fp16(x@Mc+c), H=4 alphas.
// blockDim = 512 (8 waves) for latency-bound occupancy.
__global__ __launch_bounds__(512) void k_scatter_fuse(
    const int* __restrict__ src, const int* __restrict__ dst,
    int E, int NB, int cap, int* cursor,
    unsigned int* __restrict__ ebuf,
    const float* __restrict__ x,
    const float* __restrict__ encW, const float* __restrict__ encb,
    const float* __restrict__ g1W,
    const float* __restrict__ g1as, const float* __restrict__ g1ad,
    const float* __restrict__ g2W,
    const float* __restrict__ g2as, const float* __restrict__ g2ad,
    float* __restrict__ vsd,
    __half* __restrict__ hw, float* __restrict__ alpha_s,
    float* __restrict__ alpha_d, int n){
  __shared__ int hist[800];
  __shared__ int base[800];
  __shared__ float McS[192];
  int t = threadIdx.x;                  // blockDim = 512
  if (t < 64){                          // per-block Mc (g1W is L2-resident)
    float m0 = 0.f, m1 = 0.f, cc = 0.f;
    for (int k = 0; k < 64; ++k){
      float g = g1W[k * 64 + t];
      m0 = fmaf(encW[k], g, m0);
      m1 = fmaf(encW[64 + k], g, m1);
      cc = fmaf(encb[k], g, cc);
    }
    McS[t] = m0; McS[64 + t] = m1; McS[128 + t] = cc;
  }
  if (blockIdx.x == 0 && t >= 64 && t < 128){  // vsd on a different wave
    int k = t - 64;
    float vs = 0.f, vd = 0.f;
    for (int ch = 0; ch < 64; ++ch){
      float g = g2W[k * 64 + ch];
      vs = fmaf(g, g2as[ch], vs);
      vd = fmaf(g, g2ad[ch], vd);
    }
    vsd[k] = vs; vsd[64 + k] = vd;
  }
  for (int i = t; i < NB; i += 512) hist[i] = 0;
  __syncthreads();
  int cbase = blockIdx.x * 2048;
  int sv[4], bk[4], dl[4], rk[4];
  #pragma unroll
  for (int i = 0; i < 4; ++i){
    int e = cbase + i * 512 + t;
    if (e < E){
      int d = dst[e];
      sv[i] = src[e]; bk[i] = d >> 7; dl[i] = d & 127;
      rk[i] = atomicAdd(&hist[bk[i]], 1);   // rank within (block,bucket)
    } else bk[i] = -1;
  }
  __syncthreads();
  for (int i = t; i < NB; i += 512){
    int c = hist[i];
    base[i] = (c > 0) ? (i * cap + atomicAdd(&cursor[i], c)) : 0;
  }
  __syncthreads();
  #pragma unroll
  for (int i = 0; i < 4; ++i){
    if (bk[i] >= 0){
      int p = base[bk[i]] + rk[i];
      if (p < (bk[i] + 1) * cap)        // overflow guard (never fires in practice)
        ebuf[p] = (unsigned)sv[i] | ((unsigned)dl[i] << 17);
    }
  }
  // ---- fuse1 tail: grid-stride over n*64 channels ----
  int total = n * 64;
  int lane = t & 63;
  for (int idx = blockIdx.x * 512 + t; idx < total; idx += gridDim.x * 512){
    int node = idx >> 6;                // j == lane (idx base multiple of 64)
    float acc = fmaf(x[node * 2 + 0], McS[lane],
                fmaf(x[node * 2 + 1], McS[64 + lane], McS[128 + lane]));
    hw[idx] = __float2half(acc);
    float ps = acc * g1as[lane];
    float pd = acc * g1ad[lane];
    #pragma unroll
    for (int off = 1; off < 16; off <<= 1){
      ps += __shfl_xor(ps, off);
      pd += __shfl_xor(pd, off);
    }
    if ((lane & 15) == 0){
      int h = lane >> 4;
      alpha_s[node * 4 + h] = ps;
      alpha_d[node * 4 + h] = pd;
    }
  }
}

// Phase 2: one block (256 thr) per 128-node bucket. Sort in LDS ->
// rowrange (int2) + dst-sorted packed ebuf.
__global__ void k_bucket_build(const int* __restrict__ cursor, int cap, int N,
                               unsigned int* ebuf, int2* __restrict__ rowrange){
  __shared__ unsigned int ent[2700];
  __shared__ unsigned short rank[2700];
  __shared__ int cnts[128];
  __shared__ int aux[128];
  int b = blockIdx.x, t = threadIdx.x;  // blockDim = 256
  int base = b * cap;
  int cnt = cursor[b];
  if (cnt > cap) cnt = cap;
  for (int i = t; i < cnt; i += 256) ent[i] = ebuf[base + i];
  if (t < 128) cnts[t] = 0;
  __syncthreads();
  for (int i = t; i < cnt; i += 256)
    rank[i] = (unsigned short)atomicAdd(&cnts[ent[i] >> 17], 1);
  __syncthreads();
  int v = 0;
  if (t < 128){ v = cnts[t]; aux[t] = v; }
  __syncthreads();
  for (int off = 1; off < 128; off <<= 1){
    int x = 0;
    if (t < 128 && t >= off) x = aux[t - off];
    __syncthreads();
    if (t < 128) aux[t] += x;
    __syncthreads();
  }
  if (t < 128){
    int incl = aux[t];
    int node = (b << 7) + t;
    if (node < N) rowrange[node] = make_int2(base + incl - v, base + incl);
    cnts[t] = incl - v;                 // per-node segment start (no atomics)
  }
  __syncthreads();
  for (int i = t; i < cnt; i += 256){
    unsigned int en = ent[i];
    int pos = cnts[en >> 17] + (int)rank[i];
    ebuf[base + pos] = en;              // keep packed (src|dl<<17)
  }
}

// MFMA GEMM: hw2 = fp16(h1 @ g2W); alphas via factored MFMA on wave 0:
// alpha_{s,d}[node] = h1[node,:] . vsd  (B cols [v_s|v_d|0..]).
// Zero barriers, zero LDS.
__global__ __launch_bounds__(256) void k_hw_mfma(
    const __half* __restrict__ hin, const float* __restrict__ W,
    const float* __restrict__ vsd,
    __half* __restrict__ hw, float* __restrict__ alpha_s,
    float* __restrict__ alpha_d, int n){
  int t = threadIdx.x;
  int lane = t & 63, wave = t >> 6;
  int l15 = lane & 15, quad = lane >> 4;
  int ch = wave * 16 + l15;
  half8_t b0, b1;
  #pragma unroll
  for (int j = 0; j < 8; ++j){
    b0[j] = (_Float16)W[(quad * 8 + j) * 64 + ch];
    b1[j] = (_Float16)W[(quad * 8 + j + 32) * 64 + ch];
  }
  half8_t bA0 = {0,0,0,0,0,0,0,0}, bA1 = {0,0,0,0,0,0,0,0};
  if (wave == 0 && l15 < 2){
    const float* v = vsd + l15 * 64;
    #pragma unroll
    for (int j = 0; j < 8; ++j){
      bA0[j] = (_Float16)v[quad * 8 + j];
      bA1[j] = (_Float16)v[quad * 8 + j + 32];
    }
  }
  int base = blockIdx.x * 64;
  for (int it = 0; it < 4; ++it){
    int tb = base + it * 16;
    if (tb >= n) break;
    int arn = tb + l15; if (arn >= n) arn = n - 1;
    const __half* arow = hin + (size_t)arn * 64 + quad * 8;
    half8_t a0 = *(const half8_t*)arow;
    half8_t a1 = *(const half8_t*)(arow + 32);
    floatx4 acc = {0.f, 0.f, 0.f, 0.f};
    acc = __builtin_amdgcn_mfma_f32_16x16x32_f16(a0, b0, acc, 0, 0, 0);
    acc = __builtin_amdgcn_mfma_f32_16x16x32_f16(a1, b1, acc, 0, 0, 0);
    #pragma unroll
    for (int r = 0; r < 4; ++r){
      int node = tb + quad * 4 + r;
      if (node < n) hw[(size_t)node * 64 + ch] = __float2half(acc[r]);
    }
    if (wave == 0){
      floatx4 accA = {0.f, 0.f, 0.f, 0.f};
      accA = __builtin_amdgcn_mfma_f32_16x16x32_f16(a0, bA0, accA, 0, 0, 0);
      accA = __builtin_amdgcn_mfma_f32_16x16x32_f16(a1, bA1, accA, 0, 0, 0);
      if (l15 < 2){
        float* dstp = (l15 == 0) ? alpha_s : alpha_d;
        #pragma unroll
        for (int r = 0; r < 4; ++r){
          int node = tb + quad * 4 + r;
          if (node < n) dstp[node] = accA[r];
        }
      }
    }
  }
}

// Wave = 1 destination node, 8 edge-groups x 8 lanes; lane jj owns channels
// 8jj..8jj+7 (one 16B fp16 load per edge). Numerator computed in-loop from
// the L2-resident alpha tables. [R8 gather structure: best measured.]
template<int H, bool ELU_ACT>
__global__ void k_agg(const __half* __restrict__ hw,
                      const float* __restrict__ alpha_s, const float* __restrict__ alpha_d,
                      const int2* __restrict__ rowrange,
                      const unsigned int* __restrict__ ebuf,
                      const float* __restrict__ bias, __half* __restrict__ hout, int n){
  int node = (blockIdx.x * blockDim.x + threadIdx.x) >> 6;
  int lane = threadIdx.x & 63;
  int g = lane >> 3, jj = lane & 7;
  if (node >= n) return;
  int hidx = (jj * H) >> 3;                // head of channels 8jj..8jj+7
  int2 rr = rowrange[node];
  int start = rr.x, end = rr.y;
  float adn = alpha_d[node * H + hidx];
  float acc[8] = {0.f,0.f,0.f,0.f,0.f,0.f,0.f,0.f};
  float psum = 0.f;
  if (g == 0){                             // self loop (group 0 only)
    float a = alpha_s[node * H + hidx] + adn;
    a = a > 0.f ? a : 0.2f * a;
    float p = __expf(a);
    psum = p;
    float4 rv = *(const float4*)(hw + (size_t)node * 64 + jj * 8);
    const __half2* hp = (const __half2*)&rv;
    #pragma unroll
    for (int k = 0; k < 4; ++k){
      float2 f = __half22float2(hp[k]);
      acc[2 * k] = p * f.x; acc[2 * k + 1] = p * f.y;
    }
  }
  int i = start + g;
  for (; i + 8 < end; i += 16){
    unsigned int e0 = ebuf[i], e1 = ebuf[i + 8];
    int s0 = e0 & 0x1FFFF, s1 = e1 & 0x1FFFF;
    float a0 = alpha_s[s0 * H + hidx] + adn;
    float a1 = alpha_s[s1 * H + hidx] + adn;
    a0 = a0 > 0.f ? a0 : 0.2f * a0;
    a1 = a1 > 0.f ? a1 : 0.2f * a1;
    float p0 = __expf(a0), p1 = __expf(a1);
    float4 r0 = *(const float4*)(hw + (size_t)s0 * 64 + jj * 8);
    float4 r1 = *(const float4*)(hw + (size_t)s1 * 64 + jj * 8);
    const __half2* h0 = (const __half2*)&r0;
    const __half2* h1 = (const __half2*)&r1;
    psum += p0 + p1;
    #pragma unroll
    for (int k = 0; k < 4; ++k){
      float2 f0 = __half22float2(h0[k]);
      float2 f1 = __half22float2(h1[k]);
      acc[2 * k]     = fmaf(p0, f0.x, fmaf(p1, f1.x, acc[2 * k]));
      acc[2 * k + 1] = fmaf(p0, f0.y, fmaf(p1, f1.y, acc[2 * k + 1]));
    }
  }
  if (i < end){
    unsigned int en = ebuf[i];
    int s = en & 0x1FFFF;
    float a = alpha_s[s * H + hidx] + adn;
    a = a > 0.f ? a : 0.2f * a;
    float p = __expf(a);
    float4 rv = *(const float4*)(hw + (size_t)s * 64 + jj * 8);
    const __half2* hp = (const __half2*)&rv;
    psum += p;
    #pragma unroll
    for (int k = 0; k < 4; ++k){
      float2 f = __half22float2(hp[k]);
      acc[2 * k]     = fmaf(p, f.x, acc[2 * k]);
      acc[2 * k + 1] = fmaf(p, f.y, acc[2 * k + 1]);
    }
  }
  #pragma unroll
  for (int off = 8; off < 64; off <<= 1){
    psum += __shfl_xor(psum, off);
    #pragma unroll
    for (int k = 0; k < 8; ++k) acc[k] += __shfl_xor(acc[k], off);
  }
  if (g == 0){
    float inv = 1.f / (psum + 1e-16f);
    float4 bv0 = ((const float4*)bias)[2 * jj];
    float4 bv1 = ((const float4*)bias)[2 * jj + 1];
    float o[8];
    o[0] = fmaf(acc[0], inv, bv0.x); o[1] = fmaf(acc[1], inv, bv0.y);
    o[2] = fmaf(acc[2], inv, bv0.z); o[3] = fmaf(acc[3], inv, bv0.w);
    o[4] = fmaf(acc[4], inv, bv1.x); o[5] = fmaf(acc[5], inv, bv1.y);
    o[6] = fmaf(acc[6], inv, bv1.z); o[7] = fmaf(acc[7], inv, bv1.w);
    if (ELU_ACT){
      #pragma unroll
      for (int k = 0; k < 8; ++k) o[k] = o[k] > 0.f ? o[k] : (__expf(o[k]) - 1.f);
    }
    half8_t hv;
    #pragma unroll
    for (int k = 0; k < 8; ++k) hv[k] = (_Float16)o[k];
    *(half8_t*)(hout + (size_t)node * 64 + jj * 8) = hv;
  }
}

// Fused heads GEMMs over h2 (fp16): P1/P2 fp16 + node head, 6 MFMAs/wave-tile.
__global__ __launch_bounds__(256) void k_heads_mfma(
    const __half* __restrict__ h, const float* __restrict__ eoW1,
    const float* __restrict__ noW1, const float* __restrict__ nob1,
    const float* __restrict__ noW2, const float* __restrict__ nob2,
    __half* __restrict__ P1, __half* __restrict__ P2,
    float* __restrict__ outN, int n){
  __shared__ float redP[4][16][2];
  int t = threadIdx.x;
  int lane = t & 63, wave = t >> 6;
  int l15 = lane & 15, quad = lane >> 4;
  int ch = wave * 16 + l15;
  half8_t bP1a, bP1b, bP2a, bP2b, bNa, bNb;
  #pragma unroll
  for (int j = 0; j < 8; ++j){
    int k0 = quad * 8 + j, k1 = k0 + 32;
    bP1a[j] = (_Float16)eoW1[k0 * 64 + ch];
    bP1b[j] = (_Float16)eoW1[k1 * 64 + ch];
    bP2a[j] = (_Float16)eoW1[(k0 + 64) * 64 + ch];
    bP2b[j] = (_Float16)eoW1[(k1 + 64) * 64 + ch];
    bNa[j]  = (_Float16)noW1[k0 * 64 + ch];
    bNb[j]  = (_Float16)noW1[k1 * 64 + ch];
  }
  float b1v = nob1[ch];
  float w20 = noW2[ch * 2 + 0], w21 = noW2[ch * 2 + 1];
  float b20 = nob2[0], b21 = nob2[1];
  int base = blockIdx.x * 64;
  for (int it = 0; it < 4; ++it){
    int tb = base + it * 16;
    if (tb >= n) break;
    int arn = tb + l15; if (arn >= n) arn = n - 1;
    const __half* arow = h + (size_t)arn * 64 + quad * 8;
    half8_t a0 = *(const half8_t*)arow;
    half8_t a1 = *(const half8_t*)(arow + 32);
    floatx4 ac1 = {0.f,0.f,0.f,0.f}, ac2 = {0.f,0.f,0.f,0.f}, acN = {0.f,0.f,0.f,0.f};
    ac1 = __builtin_amdgcn_mfma_f32_16x16x32_f16(a0, bP1a, ac1, 0, 0, 0);
    ac1 = __builtin_amdgcn_mfma_f32_16x16x32_f16(a1, bP1b, ac1, 0, 0, 0);
    ac2 = __builtin_amdgcn_mfma_f32_16x16x32_f16(a0, bP2a, ac2, 0, 0, 0);
    ac2 = __builtin_amdgcn_mfma_f32_16x16x32_f16(a1, bP2b, ac2, 0, 0, 0);
    acN = __builtin_amdgcn_mfma_f32_16x16x32_f16(a0, bNa, acN, 0, 0, 0);
    acN = __builtin_amdgcn_mfma_f32_16x16x32_f16(a1, bNb, acN, 0, 0, 0);
    float p0[4], p1[4];
    #pragma unroll
    for (int r = 0; r < 4; ++r){
      int node = tb + quad * 4 + r;
      if (node < n){
        P1[(size_t)node * 64 + ch] = __float2half(ac1[r]);
        P2[(size_t)node * 64 + ch] = __float2half(ac2[r]);
      }
      float v = acN[r] + b1v;
      v = v > 0.f ? v : 0.01f * v;
      p0[r] = v * w20;
      p1[r] = v * w21;
      #pragma unroll
      for (int off = 1; off < 16; off <<= 1){
        p0[r] += __shfl_xor(p0[r], off);
        p1[r] += __shfl_xor(p1[r], off);
      }
    }
    if (l15 == 0){
      #pragma unroll
      for (int r = 0; r < 4; ++r){
        redP[wave][quad * 4 + r][0] = p0[r];
        redP[wave][quad * 4 + r][1] = p1[r];
      }
    }
    __syncthreads();
    if (t < 16 && tb + t < n){
      float s0 = redP[0][t][0] + redP[1][t][0] + redP[2][t][0] + redP[3][t][0];
      float s1 = redP[0][t][1] + redP[1][t][1] + redP[2][t][1] + redP[3][t][1];
      outN[(size_t)(tb + t) * 2 + 0] = tanhf(s0 + b20);
      outN[(size_t)(tb + t) * 2 + 1] = tanhf(s1 + b21);
    }
    __syncthreads();
  }
}

// 32 edges per wave-iteration: 8 groups of 8 lanes, each group handles edges
// e, e+8, e+16, e+24 (4x unroll -> 64 gathers in flight per wave).
// Per-edge MLP in packed fp16 (native _Float16 ext-vectors -> v_pk_*):
// pk_fma pre-activation, pk_max leaky, v_dot2_f32_f16 final dot (f32 acc).
// Plain cached loads/stores. [R19 config: best measured 57.8us @ 3.40TB/s]
__global__ void k_edge_head(const __half* __restrict__ P1h, const __half* __restrict__ P2h,
                            const int* __restrict__ src, const int* __restrict__ dst,
                            const float* __restrict__ eattr, const float* __restrict__ eoW1,
                            const float* __restrict__ b1, const float* __restrict__ W2,
                            const float* __restrict__ b2, float* __restrict__ out, int E){
  int lane = threadIdx.x & 63;
  int jj = lane & 7, q = lane >> 3;
  int wid = (blockIdx.x * blockDim.x + threadIdx.x) >> 6;
  int nw = (gridDim.x * blockDim.x) >> 6;

  // per-lane weight slice (channels 8jj..8jj+7) packed to half2
  const float* rA  = eoW1 + 8192 + jj * 8;   // ea.x row of eoW1
  const float* rB  = eoW1 + 8256 + jj * 8;   // ea.y row of eoW1
  const float* b1p = b1 + jj * 8;
  const float* w2p = W2 + jj * 8;
  half2_t rah[4], rbh[4], bbh[4], w2h[4];
  #pragma unroll
  for (int k = 0; k < 4; ++k){
    rah[k] = (half2_t){(_Float16)rA[2 * k],  (_Float16)rA[2 * k + 1]};
    rbh[k] = (half2_t){(_Float16)rB[2 * k],  (_Float16)rB[2 * k + 1]};
    bbh[k] = (half2_t){(_Float16)b1p[2 * k], (_Float16)b1p[2 * k + 1]};
    w2h[k] = (half2_t){(_Float16)w2p[2 * k], (_Float16)w2p[2 * k + 1]};
  }
  const half2_t slope2 = {(_Float16)0.01f, (_Float16)0.01f};
  float b2v = b2[0];

  const float4* P1q = (const float4*)P1h;
  const float4* P2q = (const float4*)P2h;
  const float2* eav = (const float2*)eattr;

  int groups = (E + 31) >> 5;
  for (int g = wid; g < groups; g += nw){
    int e0 = g * 32 + q;
    float p[4] = {0.f, 0.f, 0.f, 0.f};
    #pragma unroll
    for (int u = 0; u < 4; ++u){
      int e = e0 + u * 8;
      if (e < E){
        int s = src[e];
        int d = dst[e];
        float2 ea = eav[e];
        float4 g1 = P1q[(size_t)s * 8 + jj];
        float4 g2 = P2q[(size_t)d * 8 + jj];
        const half2_t* h1 = (const half2_t*)&g1;
        const half2_t* h2 = (const half2_t*)&g2;
        _Float16 exs = (_Float16)ea.x, eys = (_Float16)ea.y;
        half2_t ex = {exs, exs};
        half2_t ey = {eys, eys};
        float acc = 0.f;
        #pragma unroll
        for (int k = 0; k < 4; ++k){
          half2_t c = ex * rah[k] + bbh[k];        // v_pk_fma: ea.x*Wx + b1
          c = ey * rbh[k] + c;                     // + ea.y*Wy
          half2_t tv = (h1[k] + h2[k]) + c;        // + P1[s] + P2[d]
          tv = leaky2(tv, slope2);                 // leaky_relu 0.01
          acc = fdot2_acc(tv, w2h[k], acc);        // f32 dot accumulate
        }
        p[u] = acc;
      }
    }
    #pragma unroll
    for (int off = 1; off < 8; off <<= 1){
      #pragma unroll
      for (int u = 0; u < 4; ++u) p[u] += __shfl_xor(p[u], off);
    }
    if (jj == 0){
      #pragma unroll
      for (int u = 0; u < 4; ++u){
        int e = e0 + u * 8;
        if (e < E) out[e] = tanhf(p[u] + b2v);
      }
    }
  }
}

extern "C" void kernel_launch(void* const* d_in, const int* in_sizes, int n_in,
                              void* d_out, int out_size, void* d_ws, size_t ws_size,
                              hipStream_t stream){
  const float* x    = (const float*)d_in[0];
  const int*   eidx = (const int*)  d_in[1];
  const float* ea   = (const float*)d_in[2];
  const float* encW = (const float*)d_in[3];
  const float* encb = (const float*)d_in[4];
  const float* g1W  = (const float*)d_in[5];
  const float* g1as = (const float*)d_in[6];
  const float* g1ad = (const float*)d_in[7];
  const float* g1b  = (const float*)d_in[8];
  const float* g2W  = (const float*)d_in[9];
  const float* g2as = (const float*)d_in[10];
  const float* g2ad = (const float*)d_in[11];
  const float* g2b  = (const float*)d_in[12];
  const float* noW1 = (const float*)d_in[13];
  const float* nob1 = (const float*)d_in[14];
  const float* noW2 = (const float*)d_in[15];
  const float* nob2 = (const float*)d_in[16];
  const float* eoW1 = (const float*)d_in[17];
  const float* eob1 = (const float*)d_in[18];
  const float* eoW2 = (const float*)d_in[19];
  const float* eob2 = (const float*)d_in[20];

  const int N = in_sizes[0] / 2;
  const int E = in_sizes[1] / 2;
  const int* src = eidx;
  const int* dst = eidx + E;

  const int NB = (N + 127) >> 7;         // buckets of 128 nodes (<= 800)
  int avg = (E + NB - 1) / NB;
  int cap = avg + avg / 4 + 64;          // ~25% headroom
  if (cap > 2700) cap = 2700;            // LDS limit in k_bucket_build

  // workspace layout
  char* ws = (char*)d_ws;
  size_t off = 0;
  auto alloc = [&](size_t bytes) -> void* {
    void* p = ws + off;
    off = (off + bytes + 255) & ~(size_t)255;
    return p;
  };
  __half* bufA  = (__half*)alloc((size_t)N * 64 * 2);   // h1 -> h2 (fp16)
  __half* bufH  = (__half*)alloc((size_t)N * 64 * 2);   // hw1 -> hw2
  __half* P1h   = (__half*)alloc((size_t)N * 64 * 2);
  __half* P2h   = (__half*)alloc((size_t)N * 64 * 2);
  float*  as    = (float*) alloc((size_t)N * 4 * 4);
  float*  ad    = (float*) alloc((size_t)N * 4 * 4);
  int2* rowrange = (int2*) alloc((size_t)N * 8);
  unsigned int* ebuf = (unsigned int*)alloc((size_t)NB * cap * 4);   // packed entries
  int* cursor   = (int*)   alloc((size_t)NB * 4);
  float* vsd    = (float*) alloc(128 * 4);              // [g2W@g2as ; g2W@g2ad]

  // ---- CSR build phase 1 + layer-1 hw/alphas + vsd precompute (merged) ----
  hipMemsetAsync(cursor, 0, (size_t)NB * 4, stream);
  k_scatter_fuse<<<(E + 2047) / 2048, 512, 0, stream>>>(
      src, dst, E, NB, cap, cursor, ebuf,
      x, encW, encb, g1W, g1as, g1ad, g2W, g2as, g2ad, vsd, bufH, as, ad, N);
  // ---- CSR build phase 2 (lean sort) ----
  k_bucket_build<<<NB, 256, 0, stream>>>(cursor, cap, N, ebuf, rowrange);
  // ---- layer-1 aggregation + ELU (numerator inline) ----
  k_agg<4, true><<<(N + 3) / 4, 256, 0, stream>>>(bufH, as, ad,
                                                  rowrange, ebuf, g1b, bufA, N);
  // ---- GAT layer 2 (alphas via factored MFMA; numerator inline in agg) ----
  k_hw_mfma<<<(N + 63) / 64, 256, 0, stream>>>(bufA, g2W, vsd, bufH, as, ad, N);
  k_agg<1, false><<<(N + 3) / 4, 256, 0, stream>>>(bufH, as, ad,
                                                   rowrange, ebuf, g2b, bufA, N);
  // ---- heads (fused P1/P2 + node head) ----
  float* out = (float*)d_out;
  k_heads_mfma<<<(N + 63) / 64, 256, 0, stream>>>(bufA, eoW1, noW1, nob1, noW2, nob2,
                                                  P1h, P2h, out + E, N);
  k_edge_head<<<2048, 256, 0, stream>>>(P1h, P2h, src, dst, ea,
                                        eoW1, eob1, eoW2, eob2, out, E);
}

// Round 6
// 333.938 us; speedup vs baseline: 1.0681x; 1.0490x over previous
//
#include <hip/hip_runtime.h>
#include <hip/hip_fp16.h>
#include <math.h>

// ---------------------------------------------------------------------------
// GAT model forward. N=100k nodes, E=1.6M edges, HID=64.
// R22 = R21 with k_scatter_fuse scatter chunk 2048 -> 4096 edges/block
// (8/thread x 512), decoupled from the tail grid (still 782 blocks; only the
// first 391 run the scatter phases, ALL run the fuse1 grid-stride tail).
// R21 counters for scatter_fuse: 56.4us @ 1.17TB/s, VALU 9.6%, WRITE 57MB
// (9x amplification: ~2.6-entry runs scattered into 800 bucket regions, one
// 64B line per run). Bigger chunks halve the scattered lines (~32MB), halve
// cursor-atomic rounds per address (782->391) and per-edge barrier overhead.
// edge_head at its measured fabric floor (5-round ledger); untouched.
// ---------------------------------------------------------------------------

typedef _Float16 half8_t __attribute__((ext_vector_type(8)));
typedef _Float16 half2_t __attribute__((ext_vector_type(2)));
typedef float floatx4 __attribute__((ext_vector_type(4)));

#if defined(__has_builtin)
#if __has_builtin(__builtin_amdgcn_fdot2)
#define HAS_FDOT2 1
#endif
#if __has_builtin(__builtin_elementwise_max)
#define HAS_EMAX 1
#endif
#endif

static __device__ __forceinline__ float fdot2_acc(half2_t a, half2_t b, float c){
#ifdef HAS_FDOT2
  return __builtin_amdgcn_fdot2(a, b, c, false);
#else
  return fmaf((float)a[0], (float)b[0], fmaf((float)a[1], (float)b[1], c));
#endif
}

static __device__ __forceinline__ half2_t leaky2(half2_t t, half2_t slope){
#ifdef HAS_EMAX
  return __builtin_elementwise_max(t, t * slope);     // v_pk_max_f16
#else
  half2_t r;
  r[0] = t[0] > (_Float16)0 ? t[0] : t[0] * slope[0];
  r[1] = t[1] > (_Float16)0 ? t[1] : t[1] * slope[1];
  return r;
#endif
}

// Phase 1: bucket edges by dst>>7 (rank trick). Block 0 also computes
// vsd = [g2W@g2as ; g2W@g2ad]. Scatter blocks (blockIdx*4096 < E) bucket
// 4096 edges each; ALL blocks run the fuse1 grid-stride tail.
__global__ __launch_bounds__(512) void k_scatter_fuse(
    const int* __restrict__ src, const int* __restrict__ dst,
    int E, int NB, int cap, int* cursor,
    unsigned int* __restrict__ ebuf,
    const float* __restrict__ x,
    const float* __restrict__ encW, const float* __restrict__ encb,
    const float* __restrict__ g1W,
    const float* __restrict__ g1as, const float* __restrict__ g1ad,
    const float* __restrict__ g2W,
    const float* __restrict__ g2as, const float* __restrict__ g2ad,
    float* __restrict__ vsd,
    __half* __restrict__ hw, float* __restrict__ alpha_s,
    float* __restrict__ alpha_d, int n){
  __shared__ int hist[800];
  __shared__ int base[800];
  __shared__ float McS[192];
  int t = threadIdx.x;                  // blockDim = 512
  if (t < 64){                          // per-block Mc (g1W is L2-resident)
    float m0 = 0.f, m1 = 0.f, cc = 0.f;
    for (int k = 0; k < 64; ++k){
      float g = g1W[k * 64 + t];
      m0 = fmaf(encW[k], g, m0);
      m1 = fmaf(encW[64 + k], g, m1);
      cc = fmaf(encb[k], g, cc);
    }
    McS[t] = m0; McS[64 + t] = m1; McS[128 + t] = cc;
  }
  if (blockIdx.x == 0 && t >= 64 && t < 128){  // vsd on a different wave
    int k = t - 64;
    float vs = 0.f, vd = 0.f;
    for (int ch = 0; ch < 64; ++ch){
      float g = g2W[k * 64 + ch];
      vs = fmaf(g, g2as[ch], vs);
      vd = fmaf(g, g2ad[ch], vd);
    }
    vsd[k] = vs; vsd[64 + k] = vd;
  }
  int cbase = blockIdx.x * 4096;
  bool doScatter = (cbase < E);         // block-uniform
  if (doScatter){
    for (int i = t; i < NB; i += 512) hist[i] = 0;
  }
  __syncthreads();                      // McS ready (+hist zeroed)
  if (doScatter){
    int sv[8], bk[8], dl[8], rk[8];
    #pragma unroll
    for (int i = 0; i < 8; ++i){
      int e = cbase + i * 512 + t;
      if (e < E){
        int d = dst[e];
        sv[i] = src[e]; bk[i] = d >> 7; dl[i] = d & 127;
        rk[i] = atomicAdd(&hist[bk[i]], 1);   // rank within (block,bucket)
      } else bk[i] = -1;
    }
    __syncthreads();
    for (int i = t; i < NB; i += 512){
      int c = hist[i];
      base[i] = (c > 0) ? (i * cap + atomicAdd(&cursor[i], c)) : 0;
    }
    __syncthreads();
    #pragma unroll
    for (int i = 0; i < 8; ++i){
      if (bk[i] >= 0){
        int p = base[bk[i]] + rk[i];
        if (p < (bk[i] + 1) * cap)      // overflow guard (never fires in practice)
          ebuf[p] = (unsigned)sv[i] | ((unsigned)dl[i] << 17);
      }
    }
  }
  // ---- fuse1 tail: grid-stride over n*64 channels ----
  int total = n * 64;
  int lane = t & 63;
  for (int idx = blockIdx.x * 512 + t; idx < total; idx += gridDim.x * 512){
    int node = idx >> 6;                // j == lane (idx base multiple of 64)
    float acc = fmaf(x[node * 2 + 0], McS[lane],
                fmaf(x[node * 2 + 1], McS[64 + lane], McS[128 + lane]));
    hw[idx] = __float2half(acc);
    float ps = acc * g1as[lane];
    float pd = acc * g1ad[lane];
    #pragma unroll
    for (int off = 1; off < 16; off <<= 1){
      ps += __shfl_xor(ps, off);
      pd += __shfl_xor(pd, off);
    }
    if ((lane & 15) == 0){
      int h = lane >> 4;
      alpha_s[node * 4 + h] = ps;
      alpha_d[node * 4 + h] = pd;
    }
  }
}

// Phase 2: one block (256 thr) per 128-node bucket. Sort in LDS ->
// rowrange (int2) + dst-sorted packed ebuf.
__global__ void k_bucket_build(const int* __restrict__ cursor, int cap, int N,
                               unsigned int* ebuf, int2* __restrict__ rowrange){
  __shared__ unsigned int ent[2700];
  __shared__ unsigned short rank[2700];
  __shared__ int cnts[128];
  __shared__ int aux[128];
  int b = blockIdx.x, t = threadIdx.x;  // blockDim = 256
  int base = b * cap;
  int cnt = cursor[b];
  if (cnt > cap) cnt = cap;
  for (int i = t; i < cnt; i += 256) ent[i] = ebuf[base + i];
  if (t < 128) cnts[t] = 0;
  __syncthreads();
  for (int i = t; i < cnt; i += 256)
    rank[i] = (unsigned short)atomicAdd(&cnts[ent[i] >> 17], 1);
  __syncthreads();
  int v = 0;
  if (t < 128){ v = cnts[t]; aux[t] = v; }
  __syncthreads();
  for (int off = 1; off < 128; off <<= 1){
    int x = 0;
    if (t < 128 && t >= off) x = aux[t - off];
    __syncthreads();
    if (t < 128) aux[t] += x;
    __syncthreads();
  }
  if (t < 128){
    int incl = aux[t];
    int node = (b << 7) + t;
    if (node < N) rowrange[node] = make_int2(base + incl - v, base + incl);
    cnts[t] = incl - v;                 // per-node segment start (no atomics)
  }
  __syncthreads();
  for (int i = t; i < cnt; i += 256){
    unsigned int en = ent[i];
    int pos = cnts[en >> 17] + (int)rank[i];
    ebuf[base + pos] = en;              // keep packed (src|dl<<17)
  }
}

// MFMA GEMM: hw2 = fp16(h1 @ g2W); alphas via factored MFMA on wave 0:
// alpha_{s,d}[node] = h1[node,:] . vsd  (B cols [v_s|v_d|0..]).
// Zero barriers, zero LDS.
__global__ __launch_bounds__(256) void k_hw_mfma(
    const __half* __restrict__ hin, const float* __restrict__ W,
    const float* __restrict__ vsd,
    __half* __restrict__ hw, float* __restrict__ alpha_s,
    float* __restrict__ alpha_d, int n){
  int t = threadIdx.x;
  int lane = t & 63, wave = t >> 6;
  int l15 = lane & 15, quad = lane >> 4;
  int ch = wave * 16 + l15;
  half8_t b0, b1;
  #pragma unroll
  for (int j = 0; j < 8; ++j){
    b0[j] = (_Float16)W[(quad * 8 + j) * 64 + ch];
    b1[j] = (_Float16)W[(quad * 8 + j + 32) * 64 + ch];
  }
  half8_t bA0 = {0,0,0,0,0,0,0,0}, bA1 = {0,0,0,0,0,0,0,0};
  if (wave == 0 && l15 < 2){
    const float* v = vsd + l15 * 64;
    #pragma unroll
    for (int j = 0; j < 8; ++j){
      bA0[j] = (_Float16)v[quad * 8 + j];
      bA1[j] = (_Float16)v[quad * 8 + j + 32];
    }
  }
  int base = blockIdx.x * 64;
  for (int it = 0; it < 4; ++it){
    int tb = base + it * 16;
    if (tb >= n) break;
    int arn = tb + l15; if (arn >= n) arn = n - 1;
    const __half* arow = hin + (size_t)arn * 64 + quad * 8;
    half8_t a0 = *(const half8_t*)arow;
    half8_t a1 = *(const half8_t*)(arow + 32);
    floatx4 acc = {0.f, 0.f, 0.f, 0.f};
    acc = __builtin_amdgcn_mfma_f32_16x16x32_f16(a0, b0, acc, 0, 0, 0);
    acc = __builtin_amdgcn_mfma_f32_16x16x32_f16(a1, b1, acc, 0, 0, 0);
    #pragma unroll
    for (int r = 0; r < 4; ++r){
      int node = tb + quad * 4 + r;
      if (node < n) hw[(size_t)node * 64 + ch] = __float2half(acc[r]);
    }
    if (wave == 0){
      floatx4 accA = {0.f, 0.f, 0.f, 0.f};
      accA = __builtin_amdgcn_mfma_f32_16x16x32_f16(a0, bA0, accA, 0, 0, 0);
      accA = __builtin_amdgcn_mfma_f32_16x16x32_f16(a1, bA1, accA, 0, 0, 0);
      if (l15 < 2){
        float* dstp = (l15 == 0) ? alpha_s : alpha_d;
        #pragma unroll
        for (int r = 0; r < 4; ++r){
          int node = tb + quad * 4 + r;
          if (node < n) dstp[node] = accA[r];
        }
      }
    }
  }
}

// Wave = 1 destination node, 8 edge-groups x 8 lanes; lane jj owns channels
// 8jj..8jj+7 (one 16B fp16 load per edge). Numerator computed in-loop from
// the L2-resident alpha tables. [R8 gather structure: best measured.]
template<int H, bool ELU_ACT>
__global__ void k_agg(const __half* __restrict__ hw,
                      const float* __restrict__ alpha_s, const float* __restrict__ alpha_d,
                      const int2* __restrict__ rowrange,
                      const unsigned int* __restrict__ ebuf,
                      const float* __restrict__ bias, __half* __restrict__ hout, int n){
  int node = (blockIdx.x * blockDim.x + threadIdx.x) >> 6;
  int lane = threadIdx.x & 63;
  int g = lane >> 3, jj = lane & 7;
  if (node >= n) return;
  int hidx = (jj * H) >> 3;                // head of channels 8jj..8jj+7
  int2 rr = rowrange[node];
  int start = rr.x, end = rr.y;
  float adn = alpha_d[node * H + hidx];
  float acc[8] = {0.f,0.f,0.f,0.f,0.f,0.f,0.f,0.f};
  float psum = 0.f;
  if (g == 0){                             // self loop (group 0 only)
    float a = alpha_s[node * H + hidx] + adn;
    a = a > 0.f ? a : 0.2f * a;
    float p = __expf(a);
    psum = p;
    float4 rv = *(const float4*)(hw + (size_t)node * 64 + jj * 8);
    const __half2* hp = (const __half2*)&rv;
    #pragma unroll
    for (int k = 0; k < 4; ++k){
      float2 f = __half22float2(hp[k]);
      acc[2 * k] = p * f.x; acc[2 * k + 1] = p * f.y;
    }
  }
  int i = start + g;
  for (; i + 8 < end; i += 16){
    unsigned int e0 = ebuf[i], e1 = ebuf[i + 8];
    int s0 = e0 & 0x1FFFF, s1 = e1 & 0x1FFFF;
    float a0 = alpha_s[s0 * H + hidx] + adn;
    float a1 = alpha_s[s1 * H + hidx] + adn;
    a0 = a0 > 0.f ? a0 : 0.2f * a0;
    a1 = a1 > 0.f ? a1 : 0.2f * a1;
    float p0 = __expf(a0), p1 = __expf(a1);
    float4 r0 = *(const float4*)(hw + (size_t)s0 * 64 + jj * 8);
    float4 r1 = *(const float4*)(hw + (size_t)s1 * 64 + jj * 8);
    const __half2* h0 = (const __half2*)&r0;
    const __half2* h1 = (const __half2*)&r1;
    psum += p0 + p1;
    #pragma unroll
    for (int k = 0; k < 4; ++k){
      float2 f0 = __half22float2(h0[k]);
      float2 f1 = __half22float2(h1[k]);
      acc[2 * k]     = fmaf(p0, f0.x, fmaf(p1, f1.x, acc[2 * k]));
      acc[2 * k + 1] = fmaf(p0, f0.y, fmaf(p1, f1.y, acc[2 * k + 1]));
    }
  }
  if (i < end){
    unsigned int en = ebuf[i];
    int s = en & 0x1FFFF;
    float a = alpha_s[s * H + hidx] + adn;
    a = a > 0.f ? a : 0.2f * a;
    float p = __expf(a);
    float4 rv = *(const float4*)(hw + (size_t)s * 64 + jj * 8);
    const __half2* hp = (const __half2*)&rv;
    psum += p;
    #pragma unroll
    for (int k = 0; k < 4; ++k){
      float2 f = __half22float2(hp[k]);
      acc[2 * k]     = fmaf(p, f.x, acc[2 * k]);
      acc[2 * k + 1] = fmaf(p, f.y, acc[2 * k + 1]);
    }
  }
  #pragma unroll
  for (int off = 8; off < 64; off <<= 1){
    psum += __shfl_xor(psum, off);
    #pragma unroll
    for (int k = 0; k < 8; ++k) acc[k] += __shfl_xor(acc[k], off);
  }
  if (g == 0){
    float inv = 1.f / (psum + 1e-16f);
    float4 bv0 = ((const float4*)bias)[2 * jj];
    float4 bv1 = ((const float4*)bias)[2 * jj + 1];
    float o[8];
    o[0] = fmaf(acc[0], inv, bv0.x); o[1] = fmaf(acc[1], inv, bv0.y);
    o[2] = fmaf(acc[2], inv, bv0.z); o[3] = fmaf(acc[3], inv, bv0.w);
    o[4] = fmaf(acc[4], inv, bv1.x); o[5] = fmaf(acc[5], inv, bv1.y);
    o[6] = fmaf(acc[6], inv, bv1.z); o[7] = fmaf(acc[7], inv, bv1.w);
    if (ELU_ACT){
      #pragma unroll
      for (int k = 0; k < 8; ++k) o[k] = o[k] > 0.f ? o[k] : (__expf(o[k]) - 1.f);
    }
    half8_t hv;
    #pragma unroll
    for (int k = 0; k < 8; ++k) hv[k] = (_Float16)o[k];
    *(half8_t*)(hout + (size_t)node * 64 + jj * 8) = hv;
  }
}

// Fused heads GEMMs over h2 (fp16): P1/P2 fp16 + node head, 6 MFMAs/wave-tile.
__global__ __launch_bounds__(256) void k_heads_mfma(
    const __half* __restrict__ h, const float* __restrict__ eoW1,
    const float* __restrict__ noW1, const float* __restrict__ nob1,
    const float* __restrict__ noW2, const float* __restrict__ nob2,
    __half* __restrict__ P1, __half* __restrict__ P2,
    float* __restrict__ outN, int n){
  __shared__ float redP[4][16][2];
  int t = threadIdx.x;
  int lane = t & 63, wave = t >> 6;
  int l15 = lane & 15, quad = lane >> 4;
  int ch = wave * 16 + l15;
  half8_t bP1a, bP1b, bP2a, bP2b, bNa, bNb;
  #pragma unroll
  for (int j = 0; j < 8; ++j){
    int k0 = quad * 8 + j, k1 = k0 + 32;
    bP1a[j] = (_Float16)eoW1[k0 * 64 + ch];
    bP1b[j] = (_Float16)eoW1[k1 * 64 + ch];
    bP2a[j] = (_Float16)eoW1[(k0 + 64) * 64 + ch];
    bP2b[j] = (_Float16)eoW1[(k1 + 64) * 64 + ch];
    bNa[j]  = (_Float16)noW1[k0 * 64 + ch];
    bNb[j]  = (_Float16)noW1[k1 * 64 + ch];
  }
  float b1v = nob1[ch];
  float w20 = noW2[ch * 2 + 0], w21 = noW2[ch * 2 + 1];
  float b20 = nob2[0], b21 = nob2[1];
  int base = blockIdx.x * 64;
  for (int it = 0; it < 4; ++it){
    int tb = base + it * 16;
    if (tb >= n) break;
    int arn = tb + l15; if (arn >= n) arn = n - 1;
    const __half* arow = h + (size_t)arn * 64 + quad * 8;
    half8_t a0 = *(const half8_t*)arow;
    half8_t a1 = *(const half8_t*)(arow + 32);
    floatx4 ac1 = {0.f,0.f,0.f,0.f}, ac2 = {0.f,0.f,0.f,0.f}, acN = {0.f,0.f,0.f,0.f};
    ac1 = __builtin_amdgcn_mfma_f32_16x16x32_f16(a0, bP1a, ac1, 0, 0, 0);
    ac1 = __builtin_amdgcn_mfma_f32_16x16x32_f16(a1, bP1b, ac1, 0, 0, 0);
    ac2 = __builtin_amdgcn_mfma_f32_16x16x32_f16(a0, bP2a, ac2, 0, 0, 0);
    ac2 = __builtin_amdgcn_mfma_f32_16x16x32_f16(a1, bP2b, ac2, 0, 0, 0);
    acN = __builtin_amdgcn_mfma_f32_16x16x32_f16(a0, bNa, acN, 0, 0, 0);
    acN = __builtin_amdgcn_mfma_f32_16x16x32_f16(a1, bNb, acN, 0, 0, 0);
    float p0[4], p1[4];
    #pragma unroll
    for (int r = 0; r < 4; ++r){
      int node = tb + quad * 4 + r;
      if (node < n){
        P1[(size_t)node * 64 + ch] = __float2half(ac1[r]);
        P2[(size_t)node * 64 + ch] = __float2half(ac2[r]);
      }
      float v = acN[r] + b1v;
      v = v > 0.f ? v : 0.01f * v;
      p0[r] = v * w20;
      p1[r] = v * w21;
      #pragma unroll
      for (int off = 1; off < 16; off <<= 1){
        p0[r] += __shfl_xor(p0[r], off);
        p1[r] += __shfl_xor(p1[r], off);
      }
    }
    if (l15 == 0){
      #pragma unroll
      for (int r = 0; r < 4; ++r){
        redP[wave][quad * 4 + r][0] = p0[r];
        redP[wave][quad * 4 + r][1] = p1[r];
      }
    }
    __syncthreads();
    if (t < 16 && tb + t < n){
      float s0 = redP[0][t][0] + redP[1][t][0] + redP[2][t][0] + redP[3][t][0];
      float s1 = redP[0][t][1] + redP[1][t][1] + redP[2][t][1] + redP[3][t][1];
      outN[(size_t)(tb + t) * 2 + 0] = tanhf(s0 + b20);
      outN[(size_t)(tb + t) * 2 + 1] = tanhf(s1 + b21);
    }
    __syncthreads();
  }
}

// 32 edges per wave-iteration: 8 groups of 8 lanes, each group handles edges
// e, e+8, e+16, e+24 (4x unroll -> 64 gathers in flight per wave).
// Per-edge MLP in packed fp16 (native _Float16 ext-vectors -> v_pk_*):
// pk_fma pre-activation, pk_max leaky, v_dot2_f32_f16 final dot (f32 acc).
// Plain cached loads/stores. [R19 config: best measured 56.5us @ 3.48TB/s]
__global__ void k_edge_head(const __half* __restrict__ P1h, const __half* __restrict__ P2h,
                            const int* __restrict__ src, const int* __restrict__ dst,
                            const float* __restrict__ eattr, const float* __restrict__ eoW1,
                            const float* __restrict__ b1, const float* __restrict__ W2,
                            const float* __restrict__ b2, float* __restrict__ out, int E){
  int lane = threadIdx.x & 63;
  int jj = lane & 7, q = lane >> 3;
  int wid = (blockIdx.x * blockDim.x + threadIdx.x) >> 6;
  int nw = (gridDim.x * blockDim.x) >> 6;

  // per-lane weight slice (channels 8jj..8jj+7) packed to half2
  const float* rA  = eoW1 + 8192 + jj * 8;   // ea.x row of eoW1
  const float* rB  = eoW1 + 8256 + jj * 8;   // ea.y row of eoW1
  const float* b1p = b1 + jj * 8;
  const float* w2p = W2 + jj * 8;
  half2_t rah[4], rbh[4], bbh[4], w2h[4];
  #pragma unroll
  for (int k = 0; k < 4; ++k){
    rah[k] = (half2_t){(_Float16)rA[2 * k],  (_Float16)rA[2 * k + 1]};
    rbh[k] = (half2_t){(_Float16)rB[2 * k],  (_Float16)rB[2 * k + 1]};
    bbh[k] = (half2_t){(_Float16)b1p[2 * k], (_Float16)b1p[2 * k + 1]};
    w2h[k] = (half2_t){(_Float16)w2p[2 * k], (_Float16)w2p[2 * k + 1]};
  }
  const half2_t slope2 = {(_Float16)0.01f, (_Float16)0.01f};
  float b2v = b2[0];

  const float4* P1q = (const float4*)P1h;
  const float4* P2q = (const float4*)P2h;
  const float2* eav = (const float2*)eattr;

  int groups = (E + 31) >> 5;
  for (int g = wid; g < groups; g += nw){
    int e0 = g * 32 + q;
    float p[4] = {0.f, 0.f, 0.f, 0.f};
    #pragma unroll
    for (int u = 0; u < 4; ++u){
      int e = e0 + u * 8;
      if (e < E){
        int s = src[e];
        int d = dst[e];
        float2 ea = eav[e];
        float4 g1 = P1q[(size_t)s * 8 + jj];
        float4 g2 = P2q[(size_t)d * 8 + jj];
        const half2_t* h1 = (const half2_t*)&g1;
        const half2_t* h2 = (const half2_t*)&g2;
        _Float16 exs = (_Float16)ea.x, eys = (_Float16)ea.y;
        half2_t ex = {exs, exs};
        half2_t ey = {eys, eys};
        float acc = 0.f;
        #pragma unroll
        for (int k = 0; k < 4; ++k){
          half2_t c = ex * rah[k] + bbh[k];        // v_pk_fma: ea.x*Wx + b1
          c = ey * rbh[k] + c;                     // + ea.y*Wy
          half2_t tv = (h1[k] + h2[k]) + c;        // + P1[s] + P2[d]
          tv = leaky2(tv, slope2);                 // leaky_relu 0.01
          acc = fdot2_acc(tv, w2h[k], acc);        // f32 dot accumulate
        }
        p[u] = acc;
      }
    }
    #pragma unroll
    for (int off = 1; off < 8; off <<= 1){
      #pragma unroll
      for (int u = 0; u < 4; ++u) p[u] += __shfl_xor(p[u], off);
    }
    if (jj == 0){
      #pragma unroll
      for (int u = 0; u < 4; ++u){
        int e = e0 + u * 8;
        if (e < E) out[e] = tanhf(p[u] + b2v);
      }
    }
  }
}

extern "C" void kernel_launch(void* const* d_in, const int* in_sizes, int n_in,
                              void* d_out, int out_size, void* d_ws, size_t ws_size,
                              hipStream_t stream){
  const float* x    = (const float*)d_in[0];
  const int*   eidx = (const int*)  d_in[1];
  const float* ea   = (const float*)d_in[2];
  const float* encW = (const float*)d_in[3];
  const float* encb = (const float*)d_in[4];
  const float* g1W  = (const float*)d_in[5];
  const float* g1as = (const float*)d_in[6];
  const float* g1ad = (const float*)d_in[7];
  const float* g1b  = (const float*)d_in[8];
  const float* g2W  = (const float*)d_in[9];
  const float* g2as = (const float*)d_in[10];
  const float* g2ad = (const float*)d_in[11];
  const float* g2b  = (const float*)d_in[12];
  const float* noW1 = (const float*)d_in[13];
  const float* nob1 = (const float*)d_in[14];
  const float* noW2 = (const float*)d_in[15];
  const float* nob2 = (const float*)d_in[16];
  const float* eoW1 = (const float*)d_in[17];
  const float* eob1 = (const float*)d_in[18];
  const float* eoW2 = (const float*)d_in[19];
  const float* eob2 = (const float*)d_in[20];

  const int N = in_sizes[0] / 2;
  const int E = in_sizes[1] / 2;
  const int* src = eidx;
  const int* dst = eidx + E;

  const int NB = (N + 127) >> 7;         // buckets of 128 nodes (<= 800)
  int avg = (E + NB - 1) / NB;
  int cap = avg + avg / 4 + 64;          // ~25% headroom
  if (cap > 2700) cap = 2700;            // LDS limit in k_bucket_build

  // workspace layout
  char* ws = (char*)d_ws;
  size_t off = 0;
  auto alloc = [&](size_t bytes) -> void* {
    void* p = ws + off;
    off = (off + bytes + 255) & ~(size_t)255;
    return p;
  };
  __half* bufA  = (__half*)alloc((size_t)N * 64 * 2);   // h1 -> h2 (fp16)
  __half* bufH  = (__half*)alloc((size_t)N * 64 * 2);   // hw1 -> hw2
  __half* P1h   = (__half*)alloc((size_t)N * 64 * 2);
  __half* P2h   = (__half*)alloc((size_t)N * 64 * 2);
  float*  as    = (float*) alloc((size_t)N * 4 * 4);
  float*  ad    = (float*) alloc((size_t)N * 4 * 4);
  int2* rowrange = (int2*) alloc((size_t)N * 8);
  unsigned int* ebuf = (unsigned int*)alloc((size_t)NB * cap * 4);   // packed entries
  int* cursor   = (int*)   alloc((size_t)NB * 4);
  float* vsd    = (float*) alloc(128 * 4);              // [g2W@g2as ; g2W@g2ad]

  // ---- CSR build phase 1 + layer-1 hw/alphas + vsd precompute (merged) ----
  hipMemsetAsync(cursor, 0, (size_t)NB * 4, stream);
  k_scatter_fuse<<<(E + 2047) / 2048, 512, 0, stream>>>(
      src, dst, E, NB, cap, cursor, ebuf,
      x, encW, encb, g1W, g1as, g1ad, g2W, g2as, g2ad, vsd, bufH, as, ad, N);
  // ---- CSR build phase 2 (lean sort) ----
  k_bucket_build<<<NB, 256, 0, stream>>>(cursor, cap, N, ebuf, rowrange);
  // ---- layer-1 aggregation + ELU (numerator inline) ----
  k_agg<4, true><<<(N + 3) / 4, 256, 0, stream>>>(bufH, as, ad,
                                                  rowrange, ebuf, g1b, bufA, N);
  // ---- GAT layer 2 (alphas via factored MFMA; numerator inline in agg) ----
  k_hw_mfma<<<(N + 63) / 64, 256, 0, stream>>>(bufA, g2W, vsd, bufH, as, ad, N);
  k_agg<1, false><<<(N + 3) / 4, 256, 0, stream>>>(bufH, as, ad,
                                                   rowrange, ebuf, g2b, bufA, N);
  // ---- heads (fused P1/P2 + node head) ----
  float* out = (float*)d_out;
  k_heads_mfma<<<(N + 63) / 64, 256, 0, stream>>>(bufA, eoW1, noW1, nob1, noW2, nob2,
                                                  P1h, P2h, out + E, N);
  k_edge_head<<<2048, 256, 0, stream>>>(P1h, P2h, src, dst, ea,
                                        eoW1, eob1, eoW2, eob2, out, E);
}

// Round 7
// 328.300 us; speedup vs baseline: 1.0865x; 1.0172x over previous
//
#include <hip/hip_runtime.h>
#include <hip/hip_fp16.h>
#include <math.h>

// ---------------------------------------------------------------------------
// GAT model forward. N=100k nodes, E=1.6M edges, HID=64.
// R23 = R22 with scatter chunk 4096 -> 8192 edges/block (16/thread x 512).
// R22 post-mortem: chunk 2048->4096 cut total 350.3->333.9us (write-amp
// halved as predicted; scatter_fuse left the top-5). Same lever, one more
// doubling: runs/bucket ~5->~10 entries -> ebuf WRITE ~33->~21MB, cursor
// atomic rounds 391->196. Grid stays 782 (tail wave count unchanged);
// scatter blocks = 196 (x8 waves = ~6 waves/CU during scatter phase).
// edge_head untouched at its 5-round-ledgered fabric floor (56.3us/185MB).
// ---------------------------------------------------------------------------

typedef _Float16 half8_t __attribute__((ext_vector_type(8)));
typedef _Float16 half2_t __attribute__((ext_vector_type(2)));
typedef float floatx4 __attribute__((ext_vector_type(4)));

#if defined(__has_builtin)
#if __has_builtin(__builtin_amdgcn_fdot2)
#define HAS_FDOT2 1
#endif
#if __has_builtin(__builtin_elementwise_max)
#define HAS_EMAX 1
#endif
#endif

static __device__ __forceinline__ float fdot2_acc(half2_t a, half2_t b, float c){
#ifdef HAS_FDOT2
  return __builtin_amdgcn_fdot2(a, b, c, false);
#else
  return fmaf((float)a[0], (float)b[0], fmaf((float)a[1], (float)b[1], c));
#endif
}

static __device__ __forceinline__ half2_t leaky2(half2_t t, half2_t slope){
#ifdef HAS_EMAX
  return __builtin_elementwise_max(t, t * slope);     // v_pk_max_f16
#else
  half2_t r;
  r[0] = t[0] > (_Float16)0 ? t[0] : t[0] * slope[0];
  r[1] = t[1] > (_Float16)0 ? t[1] : t[1] * slope[1];
  return r;
#endif
}

// Phase 1: bucket edges by dst>>7 (rank trick). Block 0 also computes
// vsd = [g2W@g2as ; g2W@g2ad]. Scatter blocks (blockIdx*8192 < E) bucket
// 8192 edges each; ALL blocks run the fuse1 grid-stride tail.
__global__ __launch_bounds__(512) void k_scatter_fuse(
    const int* __restrict__ src, const int* __restrict__ dst,
    int E, int NB, int cap, int* cursor,
    unsigned int* __restrict__ ebuf,
    const float* __restrict__ x,
    const float* __restrict__ encW, const float* __restrict__ encb,
    const float* __restrict__ g1W,
    const float* __restrict__ g1as, const float* __restrict__ g1ad,
    const float* __restrict__ g2W,
    const float* __restrict__ g2as, const float* __restrict__ g2ad,
    float* __restrict__ vsd,
    __half* __restrict__ hw, float* __restrict__ alpha_s,
    float* __restrict__ alpha_d, int n){
  __shared__ int hist[800];
  __shared__ int base[800];
  __shared__ float McS[192];
  int t = threadIdx.x;                  // blockDim = 512
  if (t < 64){                          // per-block Mc (g1W is L2-resident)
    float m0 = 0.f, m1 = 0.f, cc = 0.f;
    for (int k = 0; k < 64; ++k){
      float g = g1W[k * 64 + t];
      m0 = fmaf(encW[k], g, m0);
      m1 = fmaf(encW[64 + k], g, m1);
      cc = fmaf(encb[k], g, cc);
    }
    McS[t] = m0; McS[64 + t] = m1; McS[128 + t] = cc;
  }
  if (blockIdx.x == 0 && t >= 64 && t < 128){  // vsd on a different wave
    int k = t - 64;
    float vs = 0.f, vd = 0.f;
    for (int ch = 0; ch < 64; ++ch){
      float g = g2W[k * 64 + ch];
      vs = fmaf(g, g2as[ch], vs);
      vd = fmaf(g, g2ad[ch], vd);
    }
    vsd[k] = vs; vsd[64 + k] = vd;
  }
  int cbase = blockIdx.x * 8192;
  bool doScatter = (cbase < E);         // block-uniform
  if (doScatter){
    for (int i = t; i < NB; i += 512) hist[i] = 0;
  }
  __syncthreads();                      // McS ready (+hist zeroed)
  if (doScatter){
    int sv[16], bk[16], dl[16], rk[16];
    #pragma unroll
    for (int i = 0; i < 16; ++i){
      int e = cbase + i * 512 + t;
      if (e < E){
        int d = dst[e];
        sv[i] = src[e]; bk[i] = d >> 7; dl[i] = d & 127;
        rk[i] = atomicAdd(&hist[bk[i]], 1);   // rank within (block,bucket)
      } else bk[i] = -1;
    }
    __syncthreads();
    for (int i = t; i < NB; i += 512){
      int c = hist[i];
      base[i] = (c > 0) ? (i * cap + atomicAdd(&cursor[i], c)) : 0;
    }
    __syncthreads();
    #pragma unroll
    for (int i = 0; i < 16; ++i){
      if (bk[i] >= 0){
        int p = base[bk[i]] + rk[i];
        if (p < (bk[i] + 1) * cap)      // overflow guard (never fires in practice)
          ebuf[p] = (unsigned)sv[i] | ((unsigned)dl[i] << 17);
      }
    }
  }
  // ---- fuse1 tail: grid-stride over n*64 channels ----
  int total = n * 64;
  int lane = t & 63;
  for (int idx = blockIdx.x * 512 + t; idx < total; idx += gridDim.x * 512){
    int node = idx >> 6;                // j == lane (idx base multiple of 64)
    float acc = fmaf(x[node * 2 + 0], McS[lane],
                fmaf(x[node * 2 + 1], McS[64 + lane], McS[128 + lane]));
    hw[idx] = __float2half(acc);
    float ps = acc * g1as[lane];
    float pd = acc * g1ad[lane];
    #pragma unroll
    for (int off = 1; off < 16; off <<= 1){
      ps += __shfl_xor(ps, off);
      pd += __shfl_xor(pd, off);
    }
    if ((lane & 15) == 0){
      int h = lane >> 4;
      alpha_s[node * 4 + h] = ps;
      alpha_d[node * 4 + h] = pd;
    }
  }
}

// Phase 2: one block (256 thr) per 128-node bucket. Sort in LDS ->
// rowrange (int2) + dst-sorted packed ebuf.
__global__ void k_bucket_build(const int* __restrict__ cursor, int cap, int N,
                               unsigned int* ebuf, int2* __restrict__ rowrange){
  __shared__ unsigned int ent[2700];
  __shared__ unsigned short rank[2700];
  __shared__ int cnts[128];
  __shared__ int aux[128];
  int b = blockIdx.x, t = threadIdx.x;  // blockDim = 256
  int base = b * cap;
  int cnt = cursor[b];
  if (cnt > cap) cnt = cap;
  for (int i = t; i < cnt; i += 256) ent[i] = ebuf[base + i];
  if (t < 128) cnts[t] = 0;
  __syncthreads();
  for (int i = t; i < cnt; i += 256)
    rank[i] = (unsigned short)atomicAdd(&cnts[ent[i] >> 17], 1);
  __syncthreads();
  int v = 0;
  if (t < 128){ v = cnts[t]; aux[t] = v; }
  __syncthreads();
  for (int off = 1; off < 128; off <<= 1){
    int x = 0;
    if (t < 128 && t >= off) x = aux[t - off];
    __syncthreads();
    if (t < 128) aux[t] += x;
    __syncthreads();
  }
  if (t < 128){
    int incl = aux[t];
    int node = (b << 7) + t;
    if (node < N) rowrange[node] = make_int2(base + incl - v, base + incl);
    cnts[t] = incl - v;                 // per-node segment start (no atomics)
  }
  __syncthreads();
  for (int i = t; i < cnt; i += 256){
    unsigned int en = ent[i];
    int pos = cnts[en >> 17] + (int)rank[i];
    ebuf[base + pos] = en;              // keep packed (src|dl<<17)
  }
}

// MFMA GEMM: hw2 = fp16(h1 @ g2W); alphas via factored MFMA on wave 0:
// alpha_{s,d}[node] = h1[node,:] . vsd  (B cols [v_s|v_d|0..]).
// Zero barriers, zero LDS.
__global__ __launch_bounds__(256) void k_hw_mfma(
    const __half* __restrict__ hin, const float* __restrict__ W,
    const float* __restrict__ vsd,
    __half* __restrict__ hw, float* __restrict__ alpha_s,
    float* __restrict__ alpha_d, int n){
  int t = threadIdx.x;
  int lane = t & 63, wave = t >> 6;
  int l15 = lane & 15, quad = lane >> 4;
  int ch = wave * 16 + l15;
  half8_t b0, b1;
  #pragma unroll
  for (int j = 0; j < 8; ++j){
    b0[j] = (_Float16)W[(quad * 8 + j) * 64 + ch];
    b1[j] = (_Float16)W[(quad * 8 + j + 32) * 64 + ch];
  }
  half8_t bA0 = {0,0,0,0,0,0,0,0}, bA1 = {0,0,0,0,0,0,0,0};
  if (wave == 0 && l15 < 2){
    const float* v = vsd + l15 * 64;
    #pragma unroll
    for (int j = 0; j < 8; ++j){
      bA0[j] = (_Float16)v[quad * 8 + j];
      bA1[j] = (_Float16)v[quad * 8 + j + 32];
    }
  }
  int base = blockIdx.x * 64;
  for (int it = 0; it < 4; ++it){
    int tb = base + it * 16;
    if (tb >= n) break;
    int arn = tb + l15; if (arn >= n) arn = n - 1;
    const __half* arow = hin + (size_t)arn * 64 + quad * 8;
    half8_t a0 = *(const half8_t*)arow;
    half8_t a1 = *(const half8_t*)(arow + 32);
    floatx4 acc = {0.f, 0.f, 0.f, 0.f};
    acc = __builtin_amdgcn_mfma_f32_16x16x32_f16(a0, b0, acc, 0, 0, 0);
    acc = __builtin_amdgcn_mfma_f32_16x16x32_f16(a1, b1, acc, 0, 0, 0);
    #pragma unroll
    for (int r = 0; r < 4; ++r){
      int node = tb + quad * 4 + r;
      if (node < n) hw[(size_t)node * 64 + ch] = __float2half(acc[r]);
    }
    if (wave == 0){
      floatx4 accA = {0.f, 0.f, 0.f, 0.f};
      accA = __builtin_amdgcn_mfma_f32_16x16x32_f16(a0, bA0, accA, 0, 0, 0);
      accA = __builtin_amdgcn_mfma_f32_16x16x32_f16(a1, bA1, accA, 0, 0, 0);
      if (l15 < 2){
        float* dstp = (l15 == 0) ? alpha_s : alpha_d;
        #pragma unroll
        for (int r = 0; r < 4; ++r){
          int node = tb + quad * 4 + r;
          if (node < n) dstp[node] = accA[r];
        }
      }
    }
  }
}

// Wave = 1 destination node, 8 edge-groups x 8 lanes; lane jj owns channels
// 8jj..8jj+7 (one 16B fp16 load per edge). Numerator computed in-loop from
// the L2-resident alpha tables. [R8 gather structure: best measured.]
template<int H, bool ELU_ACT>
__global__ void k_agg(const __half* __restrict__ hw,
                      const float* __restrict__ alpha_s, const float* __restrict__ alpha_d,
                      const int2* __restrict__ rowrange,
                      const unsigned int* __restrict__ ebuf,
                      const float* __restrict__ bias, __half* __restrict__ hout, int n){
  int node = (blockIdx.x * blockDim.x + threadIdx.x) >> 6;
  int lane = threadIdx.x & 63;
  int g = lane >> 3, jj = lane & 7;
  if (node >= n) return;
  int hidx = (jj * H) >> 3;                // head of channels 8jj..8jj+7
  int2 rr = rowrange[node];
  int start = rr.x, end = rr.y;
  float adn = alpha_d[node * H + hidx];
  float acc[8] = {0.f,0.f,0.f,0.f,0.f,0.f,0.f,0.f};
  float psum = 0.f;
  if (g == 0){                             // self loop (group 0 only)
    float a = alpha_s[node * H + hidx] + adn;
    a = a > 0.f ? a : 0.2f * a;
    float p = __expf(a);
    psum = p;
    float4 rv = *(const float4*)(hw + (size_t)node * 64 + jj * 8);
    const __half2* hp = (const __half2*)&rv;
    #pragma unroll
    for (int k = 0; k < 4; ++k){
      float2 f = __half22float2(hp[k]);
      acc[2 * k] = p * f.x; acc[2 * k + 1] = p * f.y;
    }
  }
  int i = start + g;
  for (; i + 8 < end; i += 16){
    unsigned int e0 = ebuf[i], e1 = ebuf[i + 8];
    int s0 = e0 & 0x1FFFF, s1 = e1 & 0x1FFFF;
    float a0 = alpha_s[s0 * H + hidx] + adn;
    float a1 = alpha_s[s1 * H + hidx] + adn;
    a0 = a0 > 0.f ? a0 : 0.2f * a0;
    a1 = a1 > 0.f ? a1 : 0.2f * a1;
    float p0 = __expf(a0), p1 = __expf(a1);
    float4 r0 = *(const float4*)(hw + (size_t)s0 * 64 + jj * 8);
    float4 r1 = *(const float4*)(hw + (size_t)s1 * 64 + jj * 8);
    const __half2* h0 = (const __half2*)&r0;
    const __half2* h1 = (const __half2*)&r1;
    psum += p0 + p1;
    #pragma unroll
    for (int k = 0; k < 4; ++k){
      float2 f0 = __half22float2(h0[k]);
      float2 f1 = __half22float2(h1[k]);
      acc[2 * k]     = fmaf(p0, f0.x, fmaf(p1, f1.x, acc[2 * k]));
      acc[2 * k + 1] = fmaf(p0, f0.y, fmaf(p1, f1.y, acc[2 * k + 1]));
    }
  }
  if (i < end){
    unsigned int en = ebuf[i];
    int s = en & 0x1FFFF;
    float a = alpha_s[s * H + hidx] + adn;
    a = a > 0.f ? a : 0.2f * a;
    float p = __expf(a);
    float4 rv = *(const float4*)(hw + (size_t)s * 64 + jj * 8);
    const __half2* hp = (const __half2*)&rv;
    psum += p;
    #pragma unroll
    for (int k = 0; k < 4; ++k){
      float2 f = __half22float2(hp[k]);
      acc[2 * k]     = fmaf(p, f.x, acc[2 * k]);
      acc[2 * k + 1] = fmaf(p, f.y, acc[2 * k + 1]);
    }
  }
  #pragma unroll
  for (int off = 8; off < 64; off <<= 1){
    psum += __shfl_xor(psum, off);
    #pragma unroll
    for (int k = 0; k < 8; ++k) acc[k] += __shfl_xor(acc[k], off);
  }
  if (g == 0){
    float inv = 1.f / (psum + 1e-16f);
    float4 bv0 = ((const float4*)bias)[2 * jj];
    float4 bv1 = ((const float4*)bias)[2 * jj + 1];
    float o[8];
    o[0] = fmaf(acc[0], inv, bv0.x); o[1] = fmaf(acc[1], inv, bv0.y);
    o[2] = fmaf(acc[2], inv, bv0.z); o[3] = fmaf(acc[3], inv, bv0.w);
    o[4] = fmaf(acc[4], inv, bv1.x); o[5] = fmaf(acc[5], inv, bv1.y);
    o[6] = fmaf(acc[6], inv, bv1.z); o[7] = fmaf(acc[7], inv, bv1.w);
    if (ELU_ACT){
      #pragma unroll
      for (int k = 0; k < 8; ++k) o[k] = o[k] > 0.f ? o[k] : (__expf(o[k]) - 1.f);
    }
    half8_t hv;
    #pragma unroll
    for (int k = 0; k < 8; ++k) hv[k] = (_Float16)o[k];
    *(half8_t*)(hout + (size_t)node * 64 + jj * 8) = hv;
  }
}

// Fused heads GEMMs over h2 (fp16): P1/P2 fp16 + node head, 6 MFMAs/wave-tile.
__global__ __launch_bounds__(256) void k_heads_mfma(
    const __half* __restrict__ h, const float* __restrict__ eoW1,
    const float* __restrict__ noW1, const float* __restrict__ nob1,
    const float* __restrict__ noW2, const float* __restrict__ nob2,
    __half* __restrict__ P1, __half* __restrict__ P2,
    float* __restrict__ outN, int n){
  __shared__ float redP[4][16][2];
  int t = threadIdx.x;
  int lane = t & 63, wave = t >> 6;
  int l15 = lane & 15, quad = lane >> 4;
  int ch = wave * 16 + l15;
  half8_t bP1a, bP1b, bP2a, bP2b, bNa, bNb;
  #pragma unroll
  for (int j = 0; j < 8; ++j){
    int k0 = quad * 8 + j, k1 = k0 + 32;
    bP1a[j] = (_Float16)eoW1[k0 * 64 + ch];
    bP1b[j] = (_Float16)eoW1[k1 * 64 + ch];
    bP2a[j] = (_Float16)eoW1[(k0 + 64) * 64 + ch];
    bP2b[j] = (_Float16)eoW1[(k1 + 64) * 64 + ch];
    bNa[j]  = (_Float16)noW1[k0 * 64 + ch];
    bNb[j]  = (_Float16)noW1[k1 * 64 + ch];
  }
  float b1v = nob1[ch];
  float w20 = noW2[ch * 2 + 0], w21 = noW2[ch * 2 + 1];
  float b20 = nob2[0], b21 = nob2[1];
  int base = blockIdx.x * 64;
  for (int it = 0; it < 4; ++it){
    int tb = base + it * 16;
    if (tb >= n) break;
    int arn = tb + l15; if (arn >= n) arn = n - 1;
    const __half* arow = h + (size_t)arn * 64 + quad * 8;
    half8_t a0 = *(const half8_t*)arow;
    half8_t a1 = *(const half8_t*)(arow + 32);
    floatx4 ac1 = {0.f,0.f,0.f,0.f}, ac2 = {0.f,0.f,0.f,0.f}, acN = {0.f,0.f,0.f,0.f};
    ac1 = __builtin_amdgcn_mfma_f32_16x16x32_f16(a0, bP1a, ac1, 0, 0, 0);
    ac1 = __builtin_amdgcn_mfma_f32_16x16x32_f16(a1, bP1b, ac1, 0, 0, 0);
    ac2 = __builtin_amdgcn_mfma_f32_16x16x32_f16(a0, bP2a, ac2, 0, 0, 0);
    ac2 = __builtin_amdgcn_mfma_f32_16x16x32_f16(a1, bP2b, ac2, 0, 0, 0);
    acN = __builtin_amdgcn_mfma_f32_16x16x32_f16(a0, bNa, acN, 0, 0, 0);
    acN = __builtin_amdgcn_mfma_f32_16x16x32_f16(a1, bNb, acN, 0, 0, 0);
    float p0[4], p1[4];
    #pragma unroll
    for (int r = 0; r < 4; ++r){
      int node = tb + quad * 4 + r;
      if (node < n){
        P1[(size_t)node * 64 + ch] = __float2half(ac1[r]);
        P2[(size_t)node * 64 + ch] = __float2half(ac2[r]);
      }
      float v = acN[r] + b1v;
      v = v > 0.f ? v : 0.01f * v;
      p0[r] = v * w20;
      p1[r] = v * w21;
      #pragma unroll
      for (int off = 1; off < 16; off <<= 1){
        p0[r] += __shfl_xor(p0[r], off);
        p1[r] += __shfl_xor(p1[r], off);
      }
    }
    if (l15 == 0){
      #pragma unroll
      for (int r = 0; r < 4; ++r){
        redP[wave][quad * 4 + r][0] = p0[r];
        redP[wave][quad * 4 + r][1] = p1[r];
      }
    }
    __syncthreads();
    if (t < 16 && tb + t < n){
      float s0 = redP[0][t][0] + redP[1][t][0] + redP[2][t][0] + redP[3][t][0];
      float s1 = redP[0][t][1] + redP[1][t][1] + redP[2][t][1] + redP[3][t][1];
      outN[(size_t)(tb + t) * 2 + 0] = tanhf(s0 + b20);
      outN[(size_t)(tb + t) * 2 + 1] = tanhf(s1 + b21);
    }
    __syncthreads();
  }
}

// 32 edges per wave-iteration: 8 groups of 8 lanes, each group handles edges
// e, e+8, e+16, e+24 (4x unroll -> 64 gathers in flight per wave).
// Per-edge MLP in packed fp16 (native _Float16 ext-vectors -> v_pk_*):
// pk_fma pre-activation, pk_max leaky, v_dot2_f32_f16 final dot (f32 acc).
// Plain cached loads/stores. [R19 config: best measured 56.5us @ 3.48TB/s]
__global__ void k_edge_head(const __half* __restrict__ P1h, const __half* __restrict__ P2h,
                            const int* __restrict__ src, const int* __restrict__ dst,
                            const float* __restrict__ eattr, const float* __restrict__ eoW1,
                            const float* __restrict__ b1, const float* __restrict__ W2,
                            const float* __restrict__ b2, float* __restrict__ out, int E){
  int lane = threadIdx.x & 63;
  int jj = lane & 7, q = lane >> 3;
  int wid = (blockIdx.x * blockDim.x + threadIdx.x) >> 6;
  int nw = (gridDim.x * blockDim.x) >> 6;

  // per-lane weight slice (channels 8jj..8jj+7) packed to half2
  const float* rA  = eoW1 + 8192 + jj * 8;   // ea.x row of eoW1
  const float* rB  = eoW1 + 8256 + jj * 8;   // ea.y row of eoW1
  const float* b1p = b1 + jj * 8;
  const float* w2p = W2 + jj * 8;
  half2_t rah[4], rbh[4], bbh[4], w2h[4];
  #pragma unroll
  for (int k = 0; k < 4; ++k){
    rah[k] = (half2_t){(_Float16)rA[2 * k],  (_Float16)rA[2 * k + 1]};
    rbh[k] = (half2_t){(_Float16)rB[2 * k],  (_Float16)rB[2 * k + 1]};
    bbh[k] = (half2_t){(_Float16)b1p[2 * k], (_Float16)b1p[2 * k + 1]};
    w2h[k] = (half2_t){(_Float16)w2p[2 * k], (_Float16)w2p[2 * k + 1]};
  }
  const half2_t slope2 = {(_Float16)0.01f, (_Float16)0.01f};
  float b2v = b2[0];

  const float4* P1q = (const float4*)P1h;
  const float4* P2q = (const float4*)P2h;
  const float2* eav = (const float2*)eattr;

  int groups = (E + 31) >> 5;
  for (int g = wid; g < groups; g += nw){
    int e0 = g * 32 + q;
    float p[4] = {0.f, 0.f, 0.f, 0.f};
    #pragma unroll
    for (int u = 0; u < 4; ++u){
      int e = e0 + u * 8;
      if (e < E){
        int s = src[e];
        int d = dst[e];
        float2 ea = eav[e];
        float4 g1 = P1q[(size_t)s * 8 + jj];
        float4 g2 = P2q[(size_t)d * 8 + jj];
        const half2_t* h1 = (const half2_t*)&g1;
        const half2_t* h2 = (const half2_t*)&g2;
        _Float16 exs = (_Float16)ea.x, eys = (_Float16)ea.y;
        half2_t ex = {exs, exs};
        half2_t ey = {eys, eys};
        float acc = 0.f;
        #pragma unroll
        for (int k = 0; k < 4; ++k){
          half2_t c = ex * rah[k] + bbh[k];        // v_pk_fma: ea.x*Wx + b1
          c = ey * rbh[k] + c;                     // + ea.y*Wy
          half2_t tv = (h1[k] + h2[k]) + c;        // + P1[s] + P2[d]
          tv = leaky2(tv, slope2);                 // leaky_relu 0.01
          acc = fdot2_acc(tv, w2h[k], acc);        // f32 dot accumulate
        }
        p[u] = acc;
      }
    }
    #pragma unroll
    for (int off = 1; off < 8; off <<= 1){
      #pragma unroll
      for (int u = 0; u < 4; ++u) p[u] += __shfl_xor(p[u], off);
    }
    if (jj == 0){
      #pragma unroll
      for (int u = 0; u < 4; ++u){
        int e = e0 + u * 8;
        if (e < E) out[e] = tanhf(p[u] + b2v);
      }
    }
  }
}

extern "C" void kernel_launch(void* const* d_in, const int* in_sizes, int n_in,
                              void* d_out, int out_size, void* d_ws, size_t ws_size,
                              hipStream_t stream){
  const float* x    = (const float*)d_in[0];
  const int*   eidx = (const int*)  d_in[1];
  const float* ea   = (const float*)d_in[2];
  const float* encW = (const float*)d_in[3];
  const float* encb = (const float*)d_in[4];
  const float* g1W  = (const float*)d_in[5];
  const float* g1as = (const float*)d_in[6];
  const float* g1ad = (const float*)d_in[7];
  const float* g1b  = (const float*)d_in[8];
  const float* g2W  = (const float*)d_in[9];
  const float* g2as = (const float*)d_in[10];
  const float* g2ad = (const float*)d_in[11];
  const float* g2b  = (const float*)d_in[12];
  const float* noW1 = (const float*)d_in[13];
  const float* nob1 = (const float*)d_in[14];
  const float* noW2 = (const float*)d_in[15];
  const float* nob2 = (const float*)d_in[16];
  const float* eoW1 = (const float*)d_in[17];
  const float* eob1 = (const float*)d_in[18];
  const float* eoW2 = (const float*)d_in[19];
  const float* eob2 = (const float*)d_in[20];

  const int N = in_sizes[0] / 2;
  const int E = in_sizes[1] / 2;
  const int* src = eidx;
  const int* dst = eidx + E;

  const int NB = (N + 127) >> 7;         // buckets of 128 nodes (<= 800)
  int avg = (E + NB - 1) / NB;
  int cap = avg + avg / 4 + 64;          // ~25% headroom
  if (cap > 2700) cap = 2700;            // LDS limit in k_bucket_build

  // workspace layout
  char* ws = (char*)d_ws;
  size_t off = 0;
  auto alloc = [&](size_t bytes) -> void* {
    void* p = ws + off;
    off = (off + bytes + 255) & ~(size_t)255;
    return p;
  };
  __half* bufA  = (__half*)alloc((size_t)N * 64 * 2);   // h1 -> h2 (fp16)
  __half* bufH  = (__half*)alloc((size_t)N * 64 * 2);   // hw1 -> hw2
  __half* P1h   = (__half*)alloc((size_t)N * 64 * 2);
  __half* P2h   = (__half*)alloc((size_t)N * 64 * 2);
  float*  as    = (float*) alloc((size_t)N * 4 * 4);
  float*  ad    = (float*) alloc((size_t)N * 4 * 4);
  int2* rowrange = (int2*) alloc((size_t)N * 8);
  unsigned int* ebuf = (unsigned int*)alloc((size_t)NB * cap * 4);   // packed entries
  int* cursor   = (int*)   alloc((size_t)NB * 4);
  float* vsd    = (float*) alloc(128 * 4);              // [g2W@g2as ; g2W@g2ad]

  // ---- CSR build phase 1 + layer-1 hw/alphas + vsd precompute (merged) ----
  hipMemsetAsync(cursor, 0, (size_t)NB * 4, stream);
  k_scatter_fuse<<<(E + 2047) / 2048, 512, 0, stream>>>(
      src, dst, E, NB, cap, cursor, ebuf,
      x, encW, encb, g1W, g1as, g1ad, g2W, g2as, g2ad, vsd, bufH, as, ad, N);
  // ---- CSR build phase 2 (lean sort) ----
  k_bucket_build<<<NB, 256, 0, stream>>>(cursor, cap, N, ebuf, rowrange);
  // ---- layer-1 aggregation + ELU (numerator inline) ----
  k_agg<4, true><<<(N + 3) / 4, 256, 0, stream>>>(bufH, as, ad,
                                                  rowrange, ebuf, g1b, bufA, N);
  // ---- GAT layer 2 (alphas via factored MFMA; numerator inline in agg) ----
  k_hw_mfma<<<(N + 63) / 64, 256, 0, stream>>>(bufA, g2W, vsd, bufH, as, ad, N);
  k_agg<1, false><<<(N + 3) / 4, 256, 0, stream>>>(bufH, as, ad,
                                                   rowrange, ebuf, g2b, bufA, N);
  // ---- heads (fused P1/P2 + node head) ----
  float* out = (float*)d_out;
  k_heads_mfma<<<(N + 63) / 64, 256, 0, stream>>>(bufA, eoW1, noW1, nob1, noW2, nob2,
                                                  P1h, P2h, out + E, N);
  k_edge_head<<<2048, 256, 0, stream>>>(P1h, P2h, src, dst, ea,
                                        eoW1, eob1, eoW2, eob2, out, E);
}